// Round 8
// baseline (583.679 us; speedup 1.0000x reference)
//
#include <hip/hip_runtime.h>
#include <hip/hip_bf16.h>

#define NN 50000
#define EE 300000
#define BN_EPS 1e-5f
#define NFW 288            // NF / Z row stride in fp16 elems (258 rounded up)
#define TWOPI_256 0.024543692606170259f  // 2*pi/256

typedef __attribute__((ext_vector_type(8))) _Float16 half8;
typedef __attribute__((ext_vector_type(4))) _Float16 half4v;
typedef __attribute__((ext_vector_type(2))) _Float16 half2v;
typedef __attribute__((ext_vector_type(4))) float f32x4;
#define MFMA16F __builtin_amdgcn_mfma_f32_16x16x32_f16

// ---- static device scratch ----
__device__ __align__(16) _Float16 g_NF[(size_t)NN * NFW];   // node rfft table, fp16
__device__ __align__(16) _Float16 g_ZS[(size_t)EE * NFW];   // dst-sorted Z rows, fp16
__device__ float g_Wle[256 * 256];                          // folded loop matrix, fp32
// B operands pre-swizzled into MFMA fragment order: [ks][ntile][lane][8]
__device__ __align__(16) unsigned short g_FB[8 * 20 * 64 * 8];   // rfft matrix F
__device__ __align__(16) unsigned short g_CB[9 * 16 * 64 * 8];   // Chat
__device__ __align__(16) unsigned short g_WLEB[8 * 16 * 64 * 8]; // W_le
// counting-sort scratch (dst sort -> segments+positions; src sort -> processing order)
__device__ int g_histD[NN], g_offD[NN + 1], g_curD[NN];
__device__ int g_histS[NN], g_offS[NN], g_curS[NN];
__device__ int g_pos[EE];    // dst-sorted position of each original edge
__device__ int g_eidx[EE];   // src-sorted processing order -> original edge id
__device__ int g_esrc[EE];   // src of src-sorted edge
__device__ int g_epos[EE];   // dst-sorted position of src-sorted edge
__device__ int g_bsum[128], g_bbase[128];

__device__ __forceinline__ void atomAddF(float* p, float v) { unsafeAtomicAdd(p, v); }

__device__ __forceinline__ unsigned short f2hu(float x) {
    union { _Float16 f; unsigned short u; } c;
    c.f = (_Float16)x;
    return c.u;
}

// ---------------------------------------------------------------------------
// convert staged fp32 regs -> fp16 MFMA A-fragments in LDS (XOR-swizzled).
// lane l of tile m, kstep ks holds A[m*16+(l&15)][32*ks+8*(l>>4)+e]. 8 chunks.
// ---------------------------------------------------------------------------
__device__ __forceinline__ void stage_write(char* A, const float4* stg, int t) {
#pragma unroll
    for (int q = 0; q < 8; ++q) {
        int idx = q * 512 + t;
        int row = idx >> 6, c4 = idx & 63;
        union { _Float16 f[4]; ushort4 u; } r;
        r.f[0] = (_Float16)stg[q].x; r.f[1] = (_Float16)stg[q].y;
        r.f[2] = (_Float16)stg[q].z; r.f[3] = (_Float16)stg[q].w;
        int ks = c4 >> 3;
        int off = ((row >> 4) * 8 + ks) * 1024 +
                  ((((((c4 >> 1) & 3) << 4) | (row & 15)) * 16) ^ (ks << 4)) +
                  (c4 & 1) * 8;
        *(ushort4*)(A + off) = r.u;
    }
}

// ---------------------------------------------------------------------------
// counting sort building blocks (pointer-parameterized; run sequentially)
// ---------------------------------------------------------------------------
__global__ __launch_bounds__(512) void histK(const int* __restrict__ key,
                                             int* __restrict__ hist, int E) {
    int e = blockIdx.x * 512 + threadIdx.x;
    if (e < E) atomicAdd(&hist[key[e]], 1);
}

__global__ __launch_bounds__(512) void scanA_kernel(const int* __restrict__ cnt,
                                                    int* __restrict__ off, int N) {
    __shared__ int arr[512];
    int t = threadIdx.x, b = blockIdx.x * 512 + t;
    int c = (b < N) ? cnt[b] : 0;
    arr[t] = c;
    __syncthreads();
#pragma unroll
    for (int o = 1; o < 512; o <<= 1) {
        int v = (t >= o) ? arr[t - o] : 0;
        __syncthreads();
        arr[t] += v;
        __syncthreads();
    }
    if (b < N) off[b] = arr[t] - c;
    if (t == 511) g_bsum[blockIdx.x] = arr[511];
}

__global__ __launch_bounds__(128) void scanB_kernel(int nblk) {
    __shared__ int arr[128];
    int t = threadIdx.x;
    int v0 = (t < nblk) ? g_bsum[t] : 0;
    arr[t] = v0;
    __syncthreads();
#pragma unroll
    for (int o = 1; o < 128; o <<= 1) {
        int v = (t >= o) ? arr[t - o] : 0;
        __syncthreads();
        arr[t] += v;
        __syncthreads();
    }
    if (t < nblk) g_bbase[t] = arr[t] - v0;
}

__global__ __launch_bounds__(512) void scanC_kernel(int* __restrict__ off,
                                                    int* __restrict__ cursor,
                                                    const int* __restrict__ cnt,
                                                    int N, int writeTotal) {
    int b = blockIdx.x * 512 + threadIdx.x;
    if (b < N) {
        int v = off[b] + g_bbase[blockIdx.x];
        off[b] = v;
        cursor[b] = v;
        if (writeTotal && b == N - 1) off[N] = v + cnt[b];
    }
}

__global__ __launch_bounds__(512) void posD_kernel(const int* __restrict__ dst, int E) {
    int e = blockIdx.x * 512 + threadIdx.x;
    if (e < E) g_pos[e] = atomicAdd(&g_curD[dst[e]], 1);
}

__global__ __launch_bounds__(512) void posS_kernel(const int* __restrict__ src, int E) {
    int e = blockIdx.x * 512 + threadIdx.x;
    if (e < E) {
        int s = src[e];
        int p = atomicAdd(&g_curS[s], 1);
        g_eidx[p] = e;
        g_esrc[p] = s;
        g_epos[p] = g_pos[e];
    }
}

// ---------------------------------------------------------------------------
// K1: W_le[j][d] = sum_k loop_rel[(j+k)%256] * w_loop[k][d]   (fp32, tiny)
// ---------------------------------------------------------------------------
__global__ __launch_bounds__(256) void wle_kernel(
    const float* __restrict__ loop_rel, const float* __restrict__ w_loop,
    float* __restrict__ W_le) {
    __shared__ float lr[256];
    const int d = threadIdx.x, j = blockIdx.x;
    lr[d] = loop_rel[d];
    __syncthreads();
    float acc = 0.f;
#pragma unroll 4
    for (int k = 0; k < 256; ++k)
        acc = fmaf(lr[(j + k) & 255], w_loop[k * 256 + d], acc);
    W_le[j * 256 + d] = acc;
}

// ---------------------------------------------------------------------------
// pack F (rfft matrix) into B-fragment order, fp16.
// ---------------------------------------------------------------------------
__global__ __launch_bounds__(512) void fb_pack() {
    int b = blockIdx.x, ks = b / 20, nt = b % 20;
    int t = threadIdx.x, lane = t >> 3, e = t & 7;
    int k = 32 * ks + 8 * (lane >> 4) + e;
    int r2 = nt * 16 + (lane & 15);
    float val = 0.f;
    if (r2 < 258) {
        int f = r2 >> 1;
        int m = (f * k) & 255;
        float s, c;
        sincosf((float)m * TWOPI_256, &s, &c);
        val = (r2 & 1) ? -s : c;
    }
    g_FB[((ks * 20 + nt) * 64 + lane) * 8 + e] = f2hu(val);
}

// ---------------------------------------------------------------------------
// pack Chat into B-fragment order, fp16.
// ---------------------------------------------------------------------------
__global__ __launch_bounds__(512) void cb_pack(const float* __restrict__ w_in) {
    __shared__ float ct[256], st[256];
    int t = threadIdx.x;
    if (t < 256) {
        float s, c;
        sincosf((float)t * TWOPI_256, &s, &c);
        ct[t] = c; st[t] = s;
    }
    __syncthreads();
    int b = blockIdx.x, ks = b / 16, nt = b % 16;
    int lane = t >> 3, e = t & 7;
    int kk = 32 * ks + 8 * (lane >> 4) + e;
    int d = nt * 16 + (lane & 15);
    float val = 0.f;
    if (kk < 258) {
        int f = kk >> 1;
        float cf = (f == 0 || f == 128) ? (1.f / 256.f) : (2.f / 256.f);
        const float* tab = (kk & 1) ? st : ct;
        float sgn = (kk & 1) ? -1.f : 1.f;
        float acc = 0.f;
        for (int k = 0; k < 256; ++k)
            acc = fmaf(tab[(f * k) & 255], w_in[k * 256 + d], acc);
        val = cf * sgn * acc;
    }
    g_CB[((ks * 16 + nt) * 64 + lane) * 8 + e] = f2hu(val);
}

// pack W_le into B-fragment order, fp16.
__global__ __launch_bounds__(512) void wleb_pack() {
    int b = blockIdx.x, ks = b / 16, nt = b % 16;
    int t = threadIdx.x, lane = t >> 3, e = t & 7;
    int k = 32 * ks + 8 * (lane >> 4) + e;
    int d = nt * 16 + (lane & 15);
    g_WLEB[((ks * 16 + nt) * 64 + lane) * 8 + e] = f2hu(g_Wle[k * 256 + d]);
}

// ---------------------------------------------------------------------------
// nfloop: per 64 node rows: NF = node @ F (store fp16),
//         d_out = node @ W_le + bias.
// ---------------------------------------------------------------------------
__global__ __launch_bounds__(512, 4) void nfloop_kernel(
    const float* __restrict__ node_ft, const float* __restrict__ w_bias,
    float* __restrict__ out, int N) {
    __shared__ char smem[32768];
    unsigned short* A = (unsigned short*)smem;
    const int t = threadIdx.x;
    const long long r0 = (long long)blockIdx.x * 64;
    {
        float4 stg[8];
#pragma unroll
        for (int q = 0; q < 8; ++q) {
            int idx = q * 512 + t;
            long long gr = r0 + (idx >> 6);
            if (gr >= N) gr = N - 1;
            stg[q] = ((const float4*)node_ft)[gr * 64 + (idx & 63)];
        }
        stage_write(smem, stg, t);
    }
    __syncthreads();

    const int lane = t & 63, w = t >> 6;
    const int mw = w >> 2, nw = w & 3;
    const int l15 = lane & 15, lg = lane >> 4;

    // GEMM-F: tiles tn = nw + 4j, tn < 17
    {
        f32x4 acc[2][5] = {};
#pragma unroll
        for (int ks = 0; ks < 8; ++ks) {
            half8 a0 = *(const half8*)((char*)A + ((2 * mw + 0) * 8 + ks) * 1024 + ((lane * 16) ^ (ks << 4)));
            half8 a1 = *(const half8*)((char*)A + ((2 * mw + 1) * 8 + ks) * 1024 + ((lane * 16) ^ (ks << 4)));
#pragma unroll
            for (int j = 0; j < 4; ++j) {
                int tn = nw + 4 * j;
                half8 bf = *(const half8*)(g_FB + ((size_t)(ks * 20 + tn) * 64 + lane) * 8);
                acc[0][j] = MFMA16F(a0, bf, acc[0][j], 0, 0, 0);
                acc[1][j] = MFMA16F(a1, bf, acc[1][j], 0, 0, 0);
            }
            if (nw == 0) {
                half8 bf = *(const half8*)(g_FB + ((size_t)(ks * 20 + 16) * 64 + lane) * 8);
                acc[0][4] = MFMA16F(a0, bf, acc[0][4], 0, 0, 0);
                acc[1][4] = MFMA16F(a1, bf, acc[1][4], 0, 0, 0);
            }
        }
#pragma unroll
        for (int mt = 0; mt < 2; ++mt)
#pragma unroll
            for (int j = 0; j < 5; ++j) {
                int tn = nw + 4 * j;
                if (tn > 16 || (j == 4 && nw != 0)) continue;
                int r2 = tn * 16 + l15;
#pragma unroll
                for (int r = 0; r < 4; ++r) {
                    long long gr = r0 + (2 * mw + mt) * 16 + lg * 4 + r;
                    if (gr < N && r2 < 258)
                        g_NF[gr * NFW + r2] = (_Float16)acc[mt][j][r];
                }
            }
    }
    // GEMM-W: write loop_msg + bias into d_out
    {
        f32x4 acc[2][4] = {};
#pragma unroll
        for (int ks = 0; ks < 8; ++ks) {
            half8 a0 = *(const half8*)((char*)A + ((2 * mw + 0) * 8 + ks) * 1024 + ((lane * 16) ^ (ks << 4)));
            half8 a1 = *(const half8*)((char*)A + ((2 * mw + 1) * 8 + ks) * 1024 + ((lane * 16) ^ (ks << 4)));
#pragma unroll
            for (int j = 0; j < 4; ++j) {
                half8 bf = *(const half8*)(g_WLEB + ((size_t)(ks * 16 + 4 * nw + j) * 64 + lane) * 8);
                acc[0][j] = MFMA16F(a0, bf, acc[0][j], 0, 0, 0);
                acc[1][j] = MFMA16F(a1, bf, acc[1][j], 0, 0, 0);
            }
        }
#pragma unroll
        for (int j = 0; j < 4; ++j) {
            const int col = (4 * nw + j) * 16 + l15;
            const float bj = w_bias[col];
#pragma unroll
            for (int mt = 0; mt < 2; ++mt)
#pragma unroll
                for (int r = 0; r < 4; ++r) {
                    long long gr = r0 + (2 * mw + mt) * 16 + lg * 4 + r;
                    if (gr < N)
                        out[gr * 256 + col] = acc[mt][j][r] + bj;
                }
        }
    }
}

// ---------------------------------------------------------------------------
// edgeA: 64 SRC-SORTED edges/block. EF = y @ F (GEMM1) -> Z = conj(NF[src])*EF
// -> fp16 Z row stored at dst-sorted position. ONE barrier, no GEMM2,
// no atomics. src-sorted order makes NF reads L1/L2-local (~6 edges/src).
// ---------------------------------------------------------------------------
__global__ __launch_bounds__(512, 4) void edgeA_kernel(
    const float* __restrict__ edge_ft, int E) {
    __shared__ char smem[32768];
    unsigned short* A = (unsigned short*)smem;

    const int t = threadIdx.x;
    const long long ebase = (long long)blockIdx.x * 64;
    const int lane = t & 63, w = t >> 6;
    const int mw = w >> 2, nw = w & 3;
    const int l15 = lane & 15, lg = lane >> 4;
    const bool odd = (l15 & 1);

    // per-row meta (precomputed by posS: no dependent chains)
    int srcv[2][4], posv[2][4];
#pragma unroll
    for (int mt = 0; mt < 2; ++mt)
#pragma unroll
        for (int r = 0; r < 4; ++r) {
            long long ge = ebase + (2 * mw + mt) * 16 + lg * 4 + r;
            if (ge >= E) ge = E - 1;
            srcv[mt][r] = g_esrc[ge];
            posv[mt][r] = g_epos[ge];
        }

    // stage edge rows (1KB-row gather via eidx)
    {
        float4 stg[8];
#pragma unroll
        for (int q = 0; q < 8; ++q) {
            long long ge = ebase + q * 8 + (t >> 6);
            if (ge >= E) ge = E - 1;
            stg[q] = ((const float4*)edge_ft)[(long long)g_eidx[ge] * 64 + (t & 63)];
        }
        stage_write(smem, stg, t);
    }
    __syncthreads();

    // GEMM1: EF tiles (tn = nw + 4j < 17)
    f32x4 acc1[2][5] = {};
#pragma unroll
    for (int ks = 0; ks < 8; ++ks) {
        half8 a0 = *(const half8*)((char*)A + ((2 * mw + 0) * 8 + ks) * 1024 + ((lane * 16) ^ (ks << 4)));
        half8 a1 = *(const half8*)((char*)A + ((2 * mw + 1) * 8 + ks) * 1024 + ((lane * 16) ^ (ks << 4)));
#pragma unroll
        for (int j = 0; j < 4; ++j) {
            int tn = nw + 4 * j;
            half8 bf = *(const half8*)(g_FB + ((size_t)(ks * 20 + tn) * 64 + lane) * 8);
            acc1[0][j] = MFMA16F(a0, bf, acc1[0][j], 0, 0, 0);
            acc1[1][j] = MFMA16F(a1, bf, acc1[1][j], 0, 0, 0);
        }
        if (nw == 0) {
            half8 bf = *(const half8*)(g_FB + ((size_t)(ks * 20 + 16) * 64 + lane) * 8);
            acc1[0][4] = MFMA16F(a0, bf, acc1[0][4], 0, 0, 0);
            acc1[1][4] = MFMA16F(a1, bf, acc1[1][4], 0, 0, 0);
        }
    }

    // Hadamard + direct Z store (even lane packs its pair -> one 4B store)
#pragma unroll
    for (int mt = 0; mt < 2; ++mt) {
#pragma unroll
        for (int j = 0; j < 5; ++j) {
            int tn = nw + 4 * j;
            if (tn >= 17) continue;
            int r2 = tn * 16 + l15;
#pragma unroll
            for (int r = 0; r < 4; ++r) {
                float own = acc1[mt][j][r];
                float oth = __shfl_xor(own, 1);
                float z = 0.f;
                if (r2 < 258) {
                    union { unsigned int u; half2v h; } cv;
                    cv.u = *(const unsigned int*)(g_NF +
                        (long long)srcv[mt][r] * NFW + (r2 & ~1));
                    float br = (float)cv.h[0], bi = (float)cv.h[1];
                    z = odd ? (br * own - bi * oth) : (br * own + bi * oth);
                }
                float zo = __shfl_xor(z, 1);
                if (!odd && r2 < 258) {
                    union { half2v h; unsigned int u; } pk;
                    pk.h[0] = (_Float16)z; pk.h[1] = (_Float16)zo;
                    *(unsigned int*)(g_ZS + (size_t)posv[mt][r] * NFW + r2) = pk.u;
                }
            }
        }
    }
}

// ---------------------------------------------------------------------------
// reduceZ: 64 nodes/block. Phase1: wave-per-node segment-sum of fp16 Z rows
// (fp32 acc), scale by norm, write fp16 A-fragments (9 k-chunks). Phase2:
// GEMM vs Chat. Phase3: h = (loop+bias from d_out) + acc; write h; BN stats.
// ---------------------------------------------------------------------------
__global__ __launch_bounds__(512) void reduceZ_kernel(
    const float* __restrict__ norm, float* __restrict__ out,
    float* __restrict__ s1g, float* __restrict__ s2g, int N) {
    __shared__ char A[36864];          // 4 M-tiles x 9 chunks x 1KB
    __shared__ float s1l[256], s2l[256];
    const int t = threadIdx.x;
    const int lane = t & 63, w = t >> 6;
    const int mw = w >> 2, nw = w & 3;
    const int l15 = lane & 15, lg = lane >> 4;

    // zero fragment region + stats
    {
        int4 zero = make_int4(0, 0, 0, 0);
#pragma unroll
        for (int q = 0; q < 5; ++q) {
            int i = q * 512 + t;
            if (i < 2304) ((int4*)A)[i] = zero;
        }
        if (t < 256) { s1l[t] = 0.f; s2l[t] = 0.f; }
    }
    __syncthreads();

    // phase 1: wave w reduces nodes blk*64 + w*8 + i
#pragma unroll 1
    for (int i = 0; i < 8; ++i) {
        int n = blockIdx.x * 64 + w * 8 + i;
        if (n >= N) break;
        const int s = g_offD[n], e2 = g_offD[n + 1];
        float4 zs = make_float4(0.f, 0.f, 0.f, 0.f);
        float zt0 = 0.f, zt1 = 0.f;
        for (int i2 = s; i2 < e2; ++i2) {
            const _Float16* zr = g_ZS + (size_t)i2 * NFW;
            half4v v = *(const half4v*)(zr + 4 * lane);
            zs.x += (float)v[0]; zs.y += (float)v[1];
            zs.z += (float)v[2]; zs.w += (float)v[3];
            if (lane == 0) {
                half2v tv = *(const half2v*)(zr + 256);
                zt0 += (float)tv[0]; zt1 += (float)tv[1];
            }
        }
        const float nrm = norm[n];
        const int row = w * 8 + i;
        {
            union { _Float16 f[4]; ushort4 u; } pk;
            pk.f[0] = (_Float16)(zs.x * nrm); pk.f[1] = (_Float16)(zs.y * nrm);
            pk.f[2] = (_Float16)(zs.z * nrm); pk.f[3] = (_Float16)(zs.w * nrm);
            int c4 = lane, ks = c4 >> 3;
            int off = ((row >> 4) * 9 + ks) * 1024 +
                      ((((((c4 >> 1) & 3) << 4) | (row & 15)) * 16) ^ (ks << 4)) +
                      (c4 & 1) * 8;
            *(ushort4*)(A + off) = pk.u;
        }
        if (lane == 0) {  // cols 256,257 -> chunk ks=8, c4=64
            union { _Float16 f[4]; ushort4 u; } pk;
            pk.f[0] = (_Float16)(zt0 * nrm); pk.f[1] = (_Float16)(zt1 * nrm);
            pk.f[2] = (_Float16)0.f; pk.f[3] = (_Float16)0.f;
            int off = ((row >> 4) * 9 + 8) * 1024 +
                      (((row & 15) * 16) ^ (8 << 4));
            *(ushort4*)(A + off) = pk.u;
        }
    }
    __syncthreads();

    // phase 2: GEMM (K = 288) vs Chat
    f32x4 acc2[2][4] = {};
#pragma unroll
    for (int ks = 0; ks < 9; ++ks) {
        half8 a0 = *(const half8*)(A + ((2 * mw + 0) * 9 + ks) * 1024 + ((lane * 16) ^ (ks << 4)));
        half8 a1 = *(const half8*)(A + ((2 * mw + 1) * 9 + ks) * 1024 + ((lane * 16) ^ (ks << 4)));
#pragma unroll
        for (int j = 0; j < 4; ++j) {
            half8 bf = *(const half8*)(g_CB + ((size_t)(ks * 16 + 4 * nw + j) * 64 + lane) * 8);
            acc2[0][j] = MFMA16F(a0, bf, acc2[0][j], 0, 0, 0);
            acc2[1][j] = MFMA16F(a1, bf, acc2[1][j], 0, 0, 0);
        }
    }

    // phase 3: h = loop+bias + agg; write; BN partial stats
    float a1s[4] = {0.f, 0.f, 0.f, 0.f}, a2s[4] = {0.f, 0.f, 0.f, 0.f};
#pragma unroll
    for (int mt = 0; mt < 2; ++mt)
#pragma unroll
        for (int r = 0; r < 4; ++r) {
            int rl = (2 * mw + mt) * 16 + lg * 4 + r;
            long long n = (long long)blockIdx.x * 64 + rl;
            if (n < N) {
#pragma unroll
                for (int j = 0; j < 4; ++j) {
                    int col = (4 * nw + j) * 16 + l15;
                    float h = out[n * 256 + col] + acc2[mt][j][r];
                    out[n * 256 + col] = h;
                    a1s[j] += h; a2s[j] += h * h;
                }
            }
        }
#pragma unroll
    for (int j = 0; j < 4; ++j) {
        int col = (4 * nw + j) * 16 + l15;
        atomicAdd(&s1l[col], a1s[j]);
        atomicAdd(&s2l[col], a2s[j]);
    }
    __syncthreads();
    if (t < 256) {
        atomAddF(&s1g[t], s1l[t]);
        atomAddF(&s2g[t], s2l[t]);
    }
}

// ---------------------------------------------------------------------------
// finalize: out = tanh((h - mean) * rsqrt(var + eps) * gamma + beta)
// ---------------------------------------------------------------------------
__global__ __launch_bounds__(256) void finalize_kernel(
    float* __restrict__ out, const float* __restrict__ s1g,
    const float* __restrict__ s2g, const float* __restrict__ gamma,
    const float* __restrict__ beta, int N) {
    long long i4 = (long long)blockIdx.x * blockDim.x + threadIdx.x;
    long long tot = (long long)N * 64;
    if (i4 >= tot) return;
    const int dg = (int)(i4 & 63);
    float4 h = ((float4*)out)[i4];
    const float4 s1 = ((const float4*)s1g)[dg];
    const float4 s2 = ((const float4*)s2g)[dg];
    const float4 g = ((const float4*)gamma)[dg];
    const float4 b = ((const float4*)beta)[dg];
    const float invN = 1.f / (float)N;
    float4 o;
    { float m = s1.x * invN; float v = s2.x * invN - m * m;
      o.x = tanhf(fmaf(h.x - m, rsqrtf(v + BN_EPS) * g.x, b.x)); }
    { float m = s1.y * invN; float v = s2.y * invN - m * m;
      o.y = tanhf(fmaf(h.y - m, rsqrtf(v + BN_EPS) * g.y, b.y)); }
    { float m = s1.z * invN; float v = s2.z * invN - m * m;
      o.z = tanhf(fmaf(h.z - m, rsqrtf(v + BN_EPS) * g.z, b.z)); }
    { float m = s1.w * invN; float v = s2.w * invN - m * m;
      o.w = tanhf(fmaf(h.w - m, rsqrtf(v + BN_EPS) * g.w, b.w)); }
    ((float4*)out)[i4] = o;
}

// ---------------------------------------------------------------------------
extern "C" void kernel_launch(void* const* d_in, const int* in_sizes, int n_in,
                              void* d_out, int out_size, void* d_ws, size_t ws_size,
                              hipStream_t stream) {
    const float* node_ft  = (const float*)d_in[0];
    const float* edge_ft  = (const float*)d_in[1];
    const float* norm     = (const float*)d_in[2];
    const float* w_loop   = (const float*)d_in[3];
    const float* w_in     = (const float*)d_in[4];
    const float* loop_rel = (const float*)d_in[5];
    const float* w_bias   = (const float*)d_in[6];
    const float* bn_gamma = (const float*)d_in[7];
    const float* bn_beta  = (const float*)d_in[8];
    const int*   src      = (const int*)d_in[9];
    const int*   dst      = (const int*)d_in[10];

    const int N = in_sizes[2];
    const int E = in_sizes[9];
    float* out = (float*)d_out;

    float* s1g = (float*)d_ws;
    float* s2g = s1g + 256;

    hipMemsetAsync(d_ws, 0, 512 * sizeof(float), stream);

    float* Wle_ptr = nullptr;
    hipGetSymbolAddress((void**)&Wle_ptr, HIP_SYMBOL(g_Wle));
    void *histD_ptr = nullptr, *histS_ptr = nullptr;
    int *offD = nullptr, *offS = nullptr, *curD = nullptr, *curS = nullptr;
    hipGetSymbolAddress(&histD_ptr, HIP_SYMBOL(g_histD));
    hipGetSymbolAddress(&histS_ptr, HIP_SYMBOL(g_histS));
    hipGetSymbolAddress((void**)&offD, HIP_SYMBOL(g_offD));
    hipGetSymbolAddress((void**)&offS, HIP_SYMBOL(g_offS));
    hipGetSymbolAddress((void**)&curD, HIP_SYMBOL(g_curD));
    hipGetSymbolAddress((void**)&curS, HIP_SYMBOL(g_curS));
    hipMemsetAsync(histD_ptr, 0, (size_t)N * sizeof(int), stream);
    hipMemsetAsync(histS_ptr, 0, (size_t)N * sizeof(int), stream);

    const int sblk = (N + 511) / 512;
    const int eblk = (E + 511) / 512;

    // dst counting sort -> g_pos, g_offD (segments)
    histK<<<eblk, 512, 0, stream>>>(dst, (int*)histD_ptr, E);
    scanA_kernel<<<sblk, 512, 0, stream>>>((int*)histD_ptr, offD, N);
    scanB_kernel<<<1, 128, 0, stream>>>(sblk);
    scanC_kernel<<<sblk, 512, 0, stream>>>(offD, curD, (int*)histD_ptr, N, 1);
    posD_kernel<<<eblk, 512, 0, stream>>>(dst, E);
    // src counting sort -> processing order (eidx/esrc/epos)
    histK<<<eblk, 512, 0, stream>>>(src, (int*)histS_ptr, E);
    scanA_kernel<<<sblk, 512, 0, stream>>>((int*)histS_ptr, offS, N);
    scanB_kernel<<<1, 128, 0, stream>>>(sblk);
    scanC_kernel<<<sblk, 512, 0, stream>>>(offS, curS, (int*)histS_ptr, N, 0);
    posS_kernel<<<eblk, 512, 0, stream>>>(src, E);

    // constant packs
    wle_kernel<<<256, 256, 0, stream>>>(loop_rel, w_loop, Wle_ptr);
    fb_pack<<<8 * 20, 512, 0, stream>>>();
    cb_pack<<<9 * 16, 512, 0, stream>>>(w_in);
    wleb_pack<<<8 * 16, 512, 0, stream>>>();

    // node pass -> NF + (loop_msg + bias) in d_out
    nfloop_kernel<<<(N + 63) / 64, 512, 0, stream>>>(node_ft, w_bias, out, N);
    // edge pass -> dst-sorted fp16 Z rows (no GEMM2, no atomics)
    edgeA_kernel<<<(E + 63) / 64, 512, 0, stream>>>(edge_ft, E);
    // node-side: segment reduce + deferred GEMM2 + h write + BN stats
    reduceZ_kernel<<<(N + 63) / 64, 512, 0, stream>>>(norm, out, s1g, s2g, N);
    finalize_kernel<<<(int)(((long long)N * 64 + 255) / 256), 256, 0, stream>>>(
        out, s1g, s2g, bn_gamma, bn_beta, N);
}

// Round 9
// 493.138 us; speedup vs baseline: 1.1836x; 1.1836x over previous
//
#include <hip/hip_runtime.h>
#include <hip/hip_bf16.h>

#define NN 50000
#define EE 300000
#define BN_EPS 1e-5f
#define NFW 288            // NF row stride in fp16 elems (258 rounded up)
#define TWOPI_256 0.024543692606170259f  // 2*pi/256

typedef __attribute__((ext_vector_type(8))) _Float16 half8;
typedef __attribute__((ext_vector_type(2))) _Float16 half2v;
typedef __attribute__((ext_vector_type(4))) float f32x4;
#define MFMA16F __builtin_amdgcn_mfma_f32_16x16x32_f16

// ---- static device scratch ----
__device__ __align__(16) _Float16 g_NF[(size_t)NN * NFW];   // node rfft table, fp16
__device__ __align__(16) _Float16 g_MSG[(size_t)EE * 256];  // dst-sorted messages, fp16
__device__ float g_Wle[256 * 256];                          // folded loop matrix, fp32
// B operands pre-swizzled into MFMA fragment order: [ks][ntile][lane][8]
__device__ __align__(16) unsigned short g_FB[8 * 20 * 64 * 8];   // rfft matrix F
__device__ __align__(16) unsigned short g_CB[9 * 16 * 64 * 8];   // Chat
__device__ __align__(16) unsigned short g_WLEB[8 * 16 * 64 * 8]; // W_le
// dst counting-sort scratch
__device__ int g_hist[NN];
__device__ int g_off[NN + 1];
__device__ int g_cursor[NN];
__device__ int g_pos[EE];     // dst-sorted position of each original edge
__device__ int g_bsum[128];
__device__ int g_bbase[128];

__device__ __forceinline__ void atomAddF(float* p, float v) { unsafeAtomicAdd(p, v); }

__device__ __forceinline__ unsigned short f2hu(float x) {
    union { _Float16 f; unsigned short u; } c;
    c.f = (_Float16)x;
    return c.u;
}

// ---------------------------------------------------------------------------
// convert staged fp32 regs -> fp16 MFMA A-fragments in LDS (XOR-swizzled).
// lane l of tile m, kstep ks holds A[m*16+(l&15)][32*ks+8*(l>>4)+e].
// ---------------------------------------------------------------------------
__device__ __forceinline__ void stage_write(char* A, const float4* stg, int t) {
#pragma unroll
    for (int q = 0; q < 8; ++q) {
        int idx = q * 512 + t;
        int row = idx >> 6, c4 = idx & 63;
        union { _Float16 f[4]; ushort4 u; } r;
        r.f[0] = (_Float16)stg[q].x; r.f[1] = (_Float16)stg[q].y;
        r.f[2] = (_Float16)stg[q].z; r.f[3] = (_Float16)stg[q].w;
        int ks = c4 >> 3;
        int off = ((row >> 4) * 8 + ks) * 1024 +
                  ((((((c4 >> 1) & 3) << 4) | (row & 15)) * 16) ^ (ks << 4)) +
                  (c4 & 1) * 8;
        *(ushort4*)(A + off) = r.u;
    }
}

// ---------------------------------------------------------------------------
// dst counting sort: hist -> 2-level exclusive scan -> positions
// ---------------------------------------------------------------------------
__global__ __launch_bounds__(512) void hist_kernel(const int* __restrict__ dst, int E) {
    int e = blockIdx.x * 512 + threadIdx.x;
    if (e < E) atomicAdd(&g_hist[dst[e]], 1);
}

__global__ __launch_bounds__(512) void scanA_kernel(int N) {
    __shared__ int arr[512];
    int t = threadIdx.x, b = blockIdx.x * 512 + t;
    int cnt = (b < N) ? g_hist[b] : 0;
    arr[t] = cnt;
    __syncthreads();
#pragma unroll
    for (int off = 1; off < 512; off <<= 1) {
        int v = (t >= off) ? arr[t - off] : 0;
        __syncthreads();
        arr[t] += v;
        __syncthreads();
    }
    if (b < N) g_off[b] = arr[t] - cnt;
    if (t == 511) g_bsum[blockIdx.x] = arr[511];
}

__global__ __launch_bounds__(128) void scanB_kernel(int nblk) {
    __shared__ int arr[128];
    int t = threadIdx.x;
    int v0 = (t < nblk) ? g_bsum[t] : 0;
    arr[t] = v0;
    __syncthreads();
#pragma unroll
    for (int off = 1; off < 128; off <<= 1) {
        int v = (t >= off) ? arr[t - off] : 0;
        __syncthreads();
        arr[t] += v;
        __syncthreads();
    }
    if (t < nblk) g_bbase[t] = arr[t] - v0;
}

__global__ __launch_bounds__(512) void scanC_kernel(int N) {
    int b = blockIdx.x * 512 + threadIdx.x;
    if (b < N) {
        int v = g_off[b] + g_bbase[blockIdx.x];
        g_off[b] = v;
        g_cursor[b] = v;
        if (b == N - 1) g_off[N] = v + g_hist[b];  // = E
    }
}

__global__ __launch_bounds__(512) void pos_kernel(const int* __restrict__ dst, int E) {
    int e = blockIdx.x * 512 + threadIdx.x;
    if (e < E) g_pos[e] = atomicAdd(&g_cursor[dst[e]], 1);
}

// ---------------------------------------------------------------------------
// K1: W_le[j][d] = sum_k loop_rel[(j+k)%256] * w_loop[k][d]   (fp32, tiny)
// ---------------------------------------------------------------------------
__global__ __launch_bounds__(256) void wle_kernel(
    const float* __restrict__ loop_rel, const float* __restrict__ w_loop,
    float* __restrict__ W_le) {
    __shared__ float lr[256];
    const int d = threadIdx.x, j = blockIdx.x;
    lr[d] = loop_rel[d];
    __syncthreads();
    float acc = 0.f;
#pragma unroll 4
    for (int k = 0; k < 256; ++k)
        acc = fmaf(lr[(j + k) & 255], w_loop[k * 256 + d], acc);
    W_le[j * 256 + d] = acc;
}

// ---------------------------------------------------------------------------
// pack F (rfft matrix) into B-fragment order, fp16.
// ---------------------------------------------------------------------------
__global__ __launch_bounds__(512) void fb_pack() {
    int b = blockIdx.x, ks = b / 20, nt = b % 20;
    int t = threadIdx.x, lane = t >> 3, e = t & 7;
    int k = 32 * ks + 8 * (lane >> 4) + e;
    int r2 = nt * 16 + (lane & 15);
    float val = 0.f;
    if (r2 < 258) {
        int f = r2 >> 1;
        int m = (f * k) & 255;
        float s, c;
        sincosf((float)m * TWOPI_256, &s, &c);
        val = (r2 & 1) ? -s : c;
    }
    g_FB[((ks * 20 + nt) * 64 + lane) * 8 + e] = f2hu(val);
}

// ---------------------------------------------------------------------------
// pack Chat into B-fragment order, fp16.
// ---------------------------------------------------------------------------
__global__ __launch_bounds__(512) void cb_pack(const float* __restrict__ w_in) {
    __shared__ float ct[256], st[256];
    int t = threadIdx.x;
    if (t < 256) {
        float s, c;
        sincosf((float)t * TWOPI_256, &s, &c);
        ct[t] = c; st[t] = s;
    }
    __syncthreads();
    int b = blockIdx.x, ks = b / 16, nt = b % 16;
    int lane = t >> 3, e = t & 7;
    int kk = 32 * ks + 8 * (lane >> 4) + e;
    int d = nt * 16 + (lane & 15);
    float val = 0.f;
    if (kk < 258) {
        int f = kk >> 1;
        float cf = (f == 0 || f == 128) ? (1.f / 256.f) : (2.f / 256.f);
        const float* tab = (kk & 1) ? st : ct;
        float sgn = (kk & 1) ? -1.f : 1.f;
        float acc = 0.f;
        for (int k = 0; k < 256; ++k)
            acc = fmaf(tab[(f * k) & 255], w_in[k * 256 + d], acc);
        val = cf * sgn * acc;
    }
    g_CB[((ks * 16 + nt) * 64 + lane) * 8 + e] = f2hu(val);
}

// pack W_le into B-fragment order, fp16.
__global__ __launch_bounds__(512) void wleb_pack() {
    int b = blockIdx.x, ks = b / 16, nt = b % 16;
    int t = threadIdx.x, lane = t >> 3, e = t & 7;
    int k = 32 * ks + 8 * (lane >> 4) + e;
    int d = nt * 16 + (lane & 15);
    g_WLEB[((ks * 16 + nt) * 64 + lane) * 8 + e] = f2hu(g_Wle[k * 256 + d]);
}

// ---------------------------------------------------------------------------
// nfloop: per 64 node rows: NF = node @ F (store fp16),
//         d_out = node @ W_le + bias.
// ---------------------------------------------------------------------------
__global__ __launch_bounds__(512, 4) void nfloop_kernel(
    const float* __restrict__ node_ft, const float* __restrict__ w_bias,
    float* __restrict__ out, int N) {
    __shared__ char smem[32768];
    unsigned short* A = (unsigned short*)smem;
    const int t = threadIdx.x;
    const long long r0 = (long long)blockIdx.x * 64;
    {
        float4 stg[8];
#pragma unroll
        for (int q = 0; q < 8; ++q) {
            int idx = q * 512 + t;
            long long gr = r0 + (idx >> 6);
            if (gr >= N) gr = N - 1;
            stg[q] = ((const float4*)node_ft)[gr * 64 + (idx & 63)];
        }
        stage_write(smem, stg, t);
    }
    __syncthreads();

    const int lane = t & 63, w = t >> 6;
    const int mw = w >> 2, nw = w & 3;
    const int l15 = lane & 15, lg = lane >> 4;

    // GEMM-F: tiles tn = nw + 4j, tn < 17
    {
        f32x4 acc[2][5] = {};
#pragma unroll
        for (int ks = 0; ks < 8; ++ks) {
            half8 a0 = *(const half8*)((char*)A + ((2 * mw + 0) * 8 + ks) * 1024 + ((lane * 16) ^ (ks << 4)));
            half8 a1 = *(const half8*)((char*)A + ((2 * mw + 1) * 8 + ks) * 1024 + ((lane * 16) ^ (ks << 4)));
#pragma unroll
            for (int j = 0; j < 4; ++j) {
                int tn = nw + 4 * j;
                half8 bf = *(const half8*)(g_FB + ((size_t)(ks * 20 + tn) * 64 + lane) * 8);
                acc[0][j] = MFMA16F(a0, bf, acc[0][j], 0, 0, 0);
                acc[1][j] = MFMA16F(a1, bf, acc[1][j], 0, 0, 0);
            }
            if (nw == 0) {
                half8 bf = *(const half8*)(g_FB + ((size_t)(ks * 20 + 16) * 64 + lane) * 8);
                acc[0][4] = MFMA16F(a0, bf, acc[0][4], 0, 0, 0);
                acc[1][4] = MFMA16F(a1, bf, acc[1][4], 0, 0, 0);
            }
        }
#pragma unroll
        for (int mt = 0; mt < 2; ++mt)
#pragma unroll
            for (int j = 0; j < 5; ++j) {
                int tn = nw + 4 * j;
                if (tn > 16 || (j == 4 && nw != 0)) continue;
                int r2 = tn * 16 + l15;
#pragma unroll
                for (int r = 0; r < 4; ++r) {
                    long long gr = r0 + (2 * mw + mt) * 16 + lg * 4 + r;
                    if (gr < N && r2 < 258)
                        g_NF[gr * NFW + r2] = (_Float16)acc[mt][j][r];
                }
            }
    }
    // GEMM-W: write loop_msg + bias into d_out
    {
        f32x4 acc[2][4] = {};
#pragma unroll
        for (int ks = 0; ks < 8; ++ks) {
            half8 a0 = *(const half8*)((char*)A + ((2 * mw + 0) * 8 + ks) * 1024 + ((lane * 16) ^ (ks << 4)));
            half8 a1 = *(const half8*)((char*)A + ((2 * mw + 1) * 8 + ks) * 1024 + ((lane * 16) ^ (ks << 4)));
#pragma unroll
            for (int j = 0; j < 4; ++j) {
                half8 bf = *(const half8*)(g_WLEB + ((size_t)(ks * 16 + 4 * nw + j) * 64 + lane) * 8);
                acc[0][j] = MFMA16F(a0, bf, acc[0][j], 0, 0, 0);
                acc[1][j] = MFMA16F(a1, bf, acc[1][j], 0, 0, 0);
            }
        }
#pragma unroll
        for (int j = 0; j < 4; ++j) {
            const int col = (4 * nw + j) * 16 + l15;
            const float bj = w_bias[col];
#pragma unroll
            for (int mt = 0; mt < 2; ++mt)
#pragma unroll
                for (int r = 0; r < 4; ++r) {
                    long long gr = r0 + (2 * mw + mt) * 16 + lg * 4 + r;
                    if (gr < N)
                        out[gr * 256 + col] = acc[mt][j][r] + bj;
                }
        }
    }
}

// ---------------------------------------------------------------------------
// edgeA: 64 natural-order edges/block. NF rows for the tile are BULK-STAGED
// into LDS (ds_write can't be sunk past the barrier -> latency forced to
// overlap staging+GEMM1). EF = y @ F -> Z = conj(NF_lds)*EF -> msg = Z @ Chat
// -> fp16 store at dst-sorted position. No atomics.
// LDS: A/Z frags 36864B | NF rows 64 x 584B (576B row + 8B bank-skew pad).
// ---------------------------------------------------------------------------
__global__ __launch_bounds__(512, 4) void edgeA_kernel(
    const float* __restrict__ edge_ft, const int* __restrict__ src, int E) {
    __shared__ char smem[36864 + 64 * 584];
    unsigned short* A = (unsigned short*)smem;
    unsigned short* Z = (unsigned short*)smem;
    char* NFL = smem + 36864;

    const int t = threadIdx.x;
    const long long ebase = (long long)blockIdx.x * 64;
    const int lane = t & 63, w = t >> 6;
    const int mw = w >> 2, nw = w & 3;
    const int l15 = lane & 15, lg = lane >> 4;
    const bool odd = (l15 & 1);

    // dst-sorted output positions for my 8 rows
    int posv[2][4];
#pragma unroll
    for (int mt = 0; mt < 2; ++mt)
#pragma unroll
        for (int r = 0; r < 4; ++r) {
            long long ge = ebase + (2 * mw + mt) * 16 + lg * 4 + r;
            if (ge >= E) ge = E - 1;
            posv[mt][r] = g_pos[ge];
        }

    // edge rows -> regs (streamed, coalesced; longest-latency loads first)
    float4 stg[8];
#pragma unroll
    for (int q = 0; q < 8; ++q) {
        long long ge = ebase + q * 8 + (t >> 6);
        if (ge >= E) ge = E - 1;
        stg[q] = ((const float4*)edge_ft)[ge * 64 + (t & 63)];
    }

    // NF rows of this tile's srcs -> LDS (64 rows x 576B, 16B coalesced).
    // 2304 16B-chunks over 512 threads.
#pragma unroll
    for (int q = 0; q < 5; ++q) {
        int idx = q * 512 + t;
        if (idx < 2304) {
            int row = idx / 36, c16 = idx - row * 36;
            long long ge = ebase + row;
            if (ge >= E) ge = E - 1;
            int srow = src[ge];
            int4 v = *(const int4*)((const char*)g_NF + (size_t)srow * 576 + c16 * 16);
            *(int4*)(NFL + row * 584 + c16 * 16) = v;
        }
    }

    stage_write(smem, stg, t);
    __syncthreads();

    // GEMM1: EF tiles (tn = nw + 4j < 17)
    f32x4 acc1[2][5] = {};
#pragma unroll
    for (int ks = 0; ks < 8; ++ks) {
        half8 a0 = *(const half8*)((char*)A + ((2 * mw + 0) * 8 + ks) * 1024 + ((lane * 16) ^ (ks << 4)));
        half8 a1 = *(const half8*)((char*)A + ((2 * mw + 1) * 8 + ks) * 1024 + ((lane * 16) ^ (ks << 4)));
#pragma unroll
        for (int j = 0; j < 4; ++j) {
            int tn = nw + 4 * j;
            half8 bf = *(const half8*)(g_FB + ((size_t)(ks * 20 + tn) * 64 + lane) * 8);
            acc1[0][j] = MFMA16F(a0, bf, acc1[0][j], 0, 0, 0);
            acc1[1][j] = MFMA16F(a1, bf, acc1[1][j], 0, 0, 0);
        }
        if (nw == 0) {
            half8 bf = *(const half8*)(g_FB + ((size_t)(ks * 20 + 16) * 64 + lane) * 8);
            acc1[0][4] = MFMA16F(a0, bf, acc1[0][4], 0, 0, 0);
            acc1[1][4] = MFMA16F(a1, bf, acc1[1][4], 0, 0, 0);
        }
    }
    __syncthreads();  // A reads done; Z may overwrite

    // Hadamard: Z = conj(NF_lds) * EF, fp16 into A-frag layout.
    // NF read: NFL + e*584 + (r2&~1)*2 -> 4 e-rows land on bank groups
    // +0/+8/+16/+24 (584B stride), conflict-free.
#pragma unroll
    for (int mt = 0; mt < 2; ++mt) {
        int tm = 2 * mw + mt;
#pragma unroll
        for (int j = 0; j < 5; ++j) {
            int tn = nw + 4 * j;
            if (tn >= 18) continue;
            int r2 = tn * 16 + l15;
#pragma unroll
            for (int r = 0; r < 4; ++r) {
                int e = tm * 16 + lg * 4 + r;
                float z = 0.f;
                if (r2 < 258) {
                    float own = acc1[mt][j][r];
                    float oth = __shfl_xor(own, 1);
                    union { unsigned int u; half2v h; } cv;
                    cv.u = *(const unsigned int*)(NFL + e * 584 + (r2 & ~1) * 2);
                    float br = (float)cv.h[0], bi = (float)cv.h[1];
                    z = odd ? (br * own - bi * oth) : (br * own + bi * oth);
                }
                int ksz = r2 >> 5;
                int off = ((e >> 4) * 9 + ksz) * 1024 +
                          ((((((r2 >> 3) & 3) << 4) | (e & 15)) * 16) ^ (ksz << 4)) +
                          (r2 & 7) * 2;
                *(unsigned short*)((char*)Z + off) = f2hu(z);
            }
        }
    }
    __syncthreads();

    // GEMM2: msg = Z @ Chat (K = 288)
    f32x4 acc2[2][4] = {};
#pragma unroll
    for (int ks = 0; ks < 9; ++ks) {
        half8 a0 = *(const half8*)((char*)Z + ((2 * mw + 0) * 9 + ks) * 1024 + ((lane * 16) ^ (ks << 4)));
        half8 a1 = *(const half8*)((char*)Z + ((2 * mw + 1) * 9 + ks) * 1024 + ((lane * 16) ^ (ks << 4)));
#pragma unroll
        for (int j = 0; j < 4; ++j) {
            half8 bf = *(const half8*)(g_CB + ((size_t)(ks * 16 + 4 * nw + j) * 64 + lane) * 8);
            acc2[0][j] = MFMA16F(a0, bf, acc2[0][j], 0, 0, 0);
            acc2[1][j] = MFMA16F(a1, bf, acc2[1][j], 0, 0, 0);
        }
    }

    // store msg rows (fp16) at sorted positions; no atomics
#pragma unroll
    for (int mt = 0; mt < 2; ++mt)
#pragma unroll
        for (int r = 0; r < 4; ++r) {
            long long ge = ebase + (2 * mw + mt) * 16 + lg * 4 + r;
            if (ge < E) {
                _Float16* mrow = g_MSG + (size_t)posv[mt][r] * 256;
#pragma unroll
                for (int j = 0; j < 4; ++j)
                    mrow[(4 * nw + j) * 16 + l15] = (_Float16)acc2[mt][j][r];
            }
        }
}

// ---------------------------------------------------------------------------
// reduceB: one wave per node (8 nodes/wave, 64 nodes/block):
//   h = out_row(loop+bias) + norm[n] * sum(sorted msg segment); write h;
//   fused BN partial stats -> block LDS -> global atomics.
// ---------------------------------------------------------------------------
__global__ __launch_bounds__(512) void reduceB_kernel(
    const float* __restrict__ norm, float* __restrict__ out,
    float* __restrict__ s1g, float* __restrict__ s2g, int N) {
    __shared__ float s1l[256], s2l[256];
    const int t = threadIdx.x;
    if (t < 256) { s1l[t] = 0.f; s2l[t] = 0.f; }
    __syncthreads();
    const int w = t >> 6, lane = t & 63;
    float a1[4] = {0.f, 0.f, 0.f, 0.f}, a2[4] = {0.f, 0.f, 0.f, 0.f};

#pragma unroll 1
    for (int i = 0; i < 8; ++i) {
        int n = blockIdx.x * 64 + w * 8 + i;
        if (n >= N) break;
        const int s = g_off[n], e2 = g_off[n + 1];
        const float nrm = norm[n];
        float4 ms = make_float4(0.f, 0.f, 0.f, 0.f);
        int i2 = s;
        for (; i2 + 1 < e2; i2 += 2) {
            half2v p0 = *(const half2v*)(g_MSG + (size_t)i2 * 256 + lane * 4);
            half2v p1 = *(const half2v*)(g_MSG + (size_t)i2 * 256 + lane * 4 + 2);
            half2v q0 = *(const half2v*)(g_MSG + (size_t)(i2 + 1) * 256 + lane * 4);
            half2v q1 = *(const half2v*)(g_MSG + (size_t)(i2 + 1) * 256 + lane * 4 + 2);
            ms.x += (float)p0[0] + (float)q0[0];
            ms.y += (float)p0[1] + (float)q0[1];
            ms.z += (float)p1[0] + (float)q1[0];
            ms.w += (float)p1[1] + (float)q1[1];
        }
        if (i2 < e2) {
            half2v p0 = *(const half2v*)(g_MSG + (size_t)i2 * 256 + lane * 4);
            half2v p1 = *(const half2v*)(g_MSG + (size_t)i2 * 256 + lane * 4 + 2);
            ms.x += (float)p0[0]; ms.y += (float)p0[1];
            ms.z += (float)p1[0]; ms.w += (float)p1[1];
        }
        float4 hv = ((const float4*)out)[(size_t)n * 64 + lane];
        hv.x = fmaf(ms.x, nrm, hv.x);
        hv.y = fmaf(ms.y, nrm, hv.y);
        hv.z = fmaf(ms.z, nrm, hv.z);
        hv.w = fmaf(ms.w, nrm, hv.w);
        ((float4*)out)[(size_t)n * 64 + lane] = hv;
        a1[0] += hv.x; a2[0] += hv.x * hv.x;
        a1[1] += hv.y; a2[1] += hv.y * hv.y;
        a1[2] += hv.z; a2[2] += hv.z * hv.z;
        a1[3] += hv.w; a2[3] += hv.w * hv.w;
    }
#pragma unroll
    for (int c = 0; c < 4; ++c) {
        atomicAdd(&s1l[lane * 4 + c], a1[c]);
        atomicAdd(&s2l[lane * 4 + c], a2[c]);
    }
    __syncthreads();
    if (t < 256) {
        atomAddF(&s1g[t], s1l[t]);
        atomAddF(&s2g[t], s2l[t]);
    }
}

// ---------------------------------------------------------------------------
// finalize: out = tanh((h - mean) * rsqrt(var + eps) * gamma + beta)
// ---------------------------------------------------------------------------
__global__ __launch_bounds__(256) void finalize_kernel(
    float* __restrict__ out, const float* __restrict__ s1g,
    const float* __restrict__ s2g, const float* __restrict__ gamma,
    const float* __restrict__ beta, int N) {
    long long i4 = (long long)blockIdx.x * blockDim.x + threadIdx.x;
    long long tot = (long long)N * 64;
    if (i4 >= tot) return;
    const int dg = (int)(i4 & 63);
    float4 h = ((float4*)out)[i4];
    const float4 s1 = ((const float4*)s1g)[dg];
    const float4 s2 = ((const float4*)s2g)[dg];
    const float4 g = ((const float4*)gamma)[dg];
    const float4 b = ((const float4*)beta)[dg];
    const float invN = 1.f / (float)N;
    float4 o;
    { float m = s1.x * invN; float v = s2.x * invN - m * m;
      o.x = tanhf(fmaf(h.x - m, rsqrtf(v + BN_EPS) * g.x, b.x)); }
    { float m = s1.y * invN; float v = s2.y * invN - m * m;
      o.y = tanhf(fmaf(h.y - m, rsqrtf(v + BN_EPS) * g.y, b.y)); }
    { float m = s1.z * invN; float v = s2.z * invN - m * m;
      o.z = tanhf(fmaf(h.z - m, rsqrtf(v + BN_EPS) * g.z, b.z)); }
    { float m = s1.w * invN; float v = s2.w * invN - m * m;
      o.w = tanhf(fmaf(h.w - m, rsqrtf(v + BN_EPS) * g.w, b.w)); }
    ((float4*)out)[i4] = o;
}

// ---------------------------------------------------------------------------
extern "C" void kernel_launch(void* const* d_in, const int* in_sizes, int n_in,
                              void* d_out, int out_size, void* d_ws, size_t ws_size,
                              hipStream_t stream) {
    const float* node_ft  = (const float*)d_in[0];
    const float* edge_ft  = (const float*)d_in[1];
    const float* norm     = (const float*)d_in[2];
    const float* w_loop   = (const float*)d_in[3];
    const float* w_in     = (const float*)d_in[4];
    const float* loop_rel = (const float*)d_in[5];
    const float* w_bias   = (const float*)d_in[6];
    const float* bn_gamma = (const float*)d_in[7];
    const float* bn_beta  = (const float*)d_in[8];
    const int*   src      = (const int*)d_in[9];
    const int*   dst      = (const int*)d_in[10];

    const int N = in_sizes[2];
    const int E = in_sizes[9];
    float* out = (float*)d_out;

    float* s1g = (float*)d_ws;
    float* s2g = s1g + 256;

    hipMemsetAsync(d_ws, 0, 512 * sizeof(float), stream);

    float* Wle_ptr = nullptr;
    hipGetSymbolAddress((void**)&Wle_ptr, HIP_SYMBOL(g_Wle));
    void* hist_ptr = nullptr;
    hipGetSymbolAddress(&hist_ptr, HIP_SYMBOL(g_hist));
    hipMemsetAsync(hist_ptr, 0, (size_t)N * sizeof(int), stream);

    const int sblk = (N + 511) / 512;
    const int eblk = (E + 511) / 512;

    // dst counting sort -> g_pos, g_off
    hist_kernel<<<eblk, 512, 0, stream>>>(dst, E);
    scanA_kernel<<<sblk, 512, 0, stream>>>(N);
    scanB_kernel<<<1, 128, 0, stream>>>(sblk);
    scanC_kernel<<<sblk, 512, 0, stream>>>(N);
    pos_kernel<<<eblk, 512, 0, stream>>>(dst, E);

    // constant packs
    wle_kernel<<<256, 256, 0, stream>>>(loop_rel, w_loop, Wle_ptr);
    fb_pack<<<8 * 20, 512, 0, stream>>>();
    cb_pack<<<9 * 16, 512, 0, stream>>>(w_in);
    wleb_pack<<<8 * 16, 512, 0, stream>>>();

    // node pass -> NF + (loop_msg + bias) in d_out
    nfloop_kernel<<<(N + 63) / 64, 512, 0, stream>>>(node_ft, w_bias, out, N);
    // edge compute -> sorted fp16 msg (no atomics, NF via LDS)
    edgeA_kernel<<<(E + 63) / 64, 512, 0, stream>>>(edge_ft, src, E);
    // per-node segment reduce + h write + fused BN stats
    reduceB_kernel<<<(N + 63) / 64, 512, 0, stream>>>(norm, out, s1g, s2g, N);
    finalize_kernel<<<(int)(((long long)N * 64 + 255) / 256), 256, 0, stream>>>(
        out, s1g, s2g, bn_gamma, bn_beta, N);
}

// Round 10
// 455.727 us; speedup vs baseline: 1.2808x; 1.0821x over previous
//
#include <hip/hip_runtime.h>
#include <hip/hip_bf16.h>

#define NN 50000
#define EE 300000
#define BN_EPS 1e-5f
#define NFW 288            // NF row stride in fp16 elems
#define TWOPI_256 0.024543692606170259f  // 2*pi/256

typedef __attribute__((ext_vector_type(8))) _Float16 half8;
typedef __attribute__((ext_vector_type(2))) _Float16 half2v;
typedef __attribute__((ext_vector_type(4))) float f32x4;
#define MFMA16F __builtin_amdgcn_mfma_f32_16x16x32_f16

// ---- static device scratch ----
__device__ __align__(16) _Float16 g_NF[(size_t)NN * NFW];  // node rfft table, fp16
__device__ float g_Wle[256 * 256];                         // folded loop matrix, fp32
__device__ float g_C256[256];                              // Chat row 256 (Nyquist), fp32
// B operands pre-swizzled into MFMA fragment order: [ks][ntile][lane][8]
__device__ __align__(16) unsigned short g_FB[8 * 20 * 64 * 8];   // rfft matrix F
__device__ __align__(16) unsigned short g_CB[9 * 16 * 64 * 8];   // Chat
__device__ __align__(16) unsigned short g_WLEB[8 * 16 * 64 * 8]; // W_le
// dst counting-sort scratch
__device__ int g_hist[NN];
__device__ int g_off[NN + 1];
__device__ int g_cursor[NN];
__device__ int g_perm[EE];
__device__ int g_bsum[128];
__device__ int g_bbase[128];

__device__ __forceinline__ void atomAddF(float* p, float v) { unsafeAtomicAdd(p, v); }

__device__ __forceinline__ unsigned short f2hu(float x) {
    union { _Float16 f; unsigned short u; } c;
    c.f = (_Float16)x;
    return c.u;
}

// ---------------------------------------------------------------------------
// staged fp32 regs -> fp16 MFMA A-fragments in LDS (XOR-swizzled), 8 chunks.
// lane l of tile m, kstep ks holds A[m*16+(l&15)][32*ks+8*(l>>4)+e].
// ---------------------------------------------------------------------------
__device__ __forceinline__ void stage_write(char* A, const float4* stg, int t) {
#pragma unroll
    for (int q = 0; q < 8; ++q) {
        int idx = q * 512 + t;
        int row = idx >> 6, c4 = idx & 63;
        union { _Float16 f[4]; ushort4 u; } r;
        r.f[0] = (_Float16)stg[q].x; r.f[1] = (_Float16)stg[q].y;
        r.f[2] = (_Float16)stg[q].z; r.f[3] = (_Float16)stg[q].w;
        int ks = c4 >> 3;
        int off = ((row >> 4) * 8 + ks) * 1024 +
                  ((((((c4 >> 1) & 3) << 4) | (row & 15)) * 16) ^ (ks << 4)) +
                  (c4 & 1) * 8;
        *(ushort4*)(A + off) = r.u;
    }
}

// full-wave sum of v across 64 lanes
__device__ __forceinline__ float waveSum(float v) {
#pragma unroll
    for (int d = 1; d < 64; d <<= 1) v += __shfl_xor(v, d);
    return v;
}

// ---------------------------------------------------------------------------
// dst counting sort: hist -> 2-level exclusive scan -> permutation
// ---------------------------------------------------------------------------
__global__ __launch_bounds__(512) void hist_kernel(const int* __restrict__ dst, int E) {
    int e = blockIdx.x * 512 + threadIdx.x;
    if (e < E) atomicAdd(&g_hist[dst[e]], 1);
}

__global__ __launch_bounds__(512) void scanA_kernel(int N) {
    __shared__ int arr[512];
    int t = threadIdx.x, b = blockIdx.x * 512 + t;
    int cnt = (b < N) ? g_hist[b] : 0;
    arr[t] = cnt;
    __syncthreads();
#pragma unroll
    for (int off = 1; off < 512; off <<= 1) {
        int v = (t >= off) ? arr[t - off] : 0;
        __syncthreads();
        arr[t] += v;
        __syncthreads();
    }
    if (b < N) g_off[b] = arr[t] - cnt;
    if (t == 511) g_bsum[blockIdx.x] = arr[511];
}

__global__ __launch_bounds__(128) void scanB_kernel(int nblk) {
    __shared__ int arr[128];
    int t = threadIdx.x;
    int v0 = (t < nblk) ? g_bsum[t] : 0;
    arr[t] = v0;
    __syncthreads();
#pragma unroll
    for (int off = 1; off < 128; off <<= 1) {
        int v = (t >= off) ? arr[t - off] : 0;
        __syncthreads();
        arr[t] += v;
        __syncthreads();
    }
    if (t < nblk) g_bbase[t] = arr[t] - v0;
}

__global__ __launch_bounds__(512) void scanC_kernel(int N) {
    int b = blockIdx.x * 512 + threadIdx.x;
    if (b < N) {
        int v = g_off[b] + g_bbase[blockIdx.x];
        g_off[b] = v;
        g_cursor[b] = v;
        if (b == N - 1) g_off[N] = v + g_hist[b];
    }
}

__global__ __launch_bounds__(512) void perm_kernel(const int* __restrict__ dst, int E) {
    int e = blockIdx.x * 512 + threadIdx.x;
    if (e < E) {
        int pos = atomicAdd(&g_cursor[dst[e]], 1);
        g_perm[pos] = e;
    }
}

// ---------------------------------------------------------------------------
// K1: W_le[j][d] = sum_k loop_rel[(j+k)%256] * w_loop[k][d]
// ---------------------------------------------------------------------------
__global__ __launch_bounds__(256) void wle_kernel(
    const float* __restrict__ loop_rel, const float* __restrict__ w_loop,
    float* __restrict__ W_le) {
    __shared__ float lr[256];
    const int d = threadIdx.x, j = blockIdx.x;
    lr[d] = loop_rel[d];
    __syncthreads();
    float acc = 0.f;
#pragma unroll 4
    for (int k = 0; k < 256; ++k)
        acc = fmaf(lr[(j + k) & 255], w_loop[k * 256 + d], acc);
    W_le[j * 256 + d] = acc;
}

// ---------------------------------------------------------------------------
// pack F into B-fragment order, fp16 (tiles 0..15 used; 16..19 packed, unused)
// ---------------------------------------------------------------------------
__global__ __launch_bounds__(512) void fb_pack() {
    int b = blockIdx.x, ks = b / 20, nt = b % 20;
    int t = threadIdx.x, lane = t >> 3, e = t & 7;
    int k = 32 * ks + 8 * (lane >> 4) + e;
    int r2 = nt * 16 + (lane & 15);
    float val = 0.f;
    if (r2 < 258) {
        int f = r2 >> 1;
        int m = (f * k) & 255;
        float s, c;
        sincosf((float)m * TWOPI_256, &s, &c);
        val = (r2 & 1) ? -s : c;
    }
    g_FB[((ks * 20 + nt) * 64 + lane) * 8 + e] = f2hu(val);
}

// ---------------------------------------------------------------------------
// pack Chat into B-fragment order, fp16; also emit fp32 row 256 -> g_C256.
// ---------------------------------------------------------------------------
__global__ __launch_bounds__(512) void cb_pack(const float* __restrict__ w_in) {
    __shared__ float ct[256], st[256];
    int t = threadIdx.x;
    if (t < 256) {
        float s, c;
        sincosf((float)t * TWOPI_256, &s, &c);
        ct[t] = c; st[t] = s;
    }
    __syncthreads();
    int b = blockIdx.x, ks = b / 16, nt = b % 16;
    int lane = t >> 3, e = t & 7;
    int kk = 32 * ks + 8 * (lane >> 4) + e;
    int d = nt * 16 + (lane & 15);
    float val = 0.f;
    if (kk < 258) {
        int f = kk >> 1;
        float cf = (f == 0 || f == 128) ? (1.f / 256.f) : (2.f / 256.f);
        const float* tab = (kk & 1) ? st : ct;
        float sgn = (kk & 1) ? -1.f : 1.f;
        float acc = 0.f;
        for (int k = 0; k < 256; ++k)
            acc = fmaf(tab[(f * k) & 255], w_in[k * 256 + d], acc);
        val = cf * sgn * acc;
    }
    if (kk == 256) g_C256[d] = val;   // Nyquist row, fp32
    g_CB[((ks * 16 + nt) * 64 + lane) * 8 + e] = f2hu(val);
}

// pack W_le into B-fragment order, fp16.
__global__ __launch_bounds__(512) void wleb_pack() {
    int b = blockIdx.x, ks = b / 16, nt = b % 16;
    int t = threadIdx.x, lane = t >> 3, e = t & 7;
    int k = 32 * ks + 8 * (lane >> 4) + e;
    int d = nt * 16 + (lane & 15);
    g_WLEB[((ks * 16 + nt) * 64 + lane) * 8 + e] = f2hu(g_Wle[k * 256 + d]);
}

// ---------------------------------------------------------------------------
// nfloop: per 64 node rows: NF = node @ F (cols 0..255 via MFMA; col 256 =
// alternating sum via wave-reduce during staging), d_out = node @ W_le + bias.
// ---------------------------------------------------------------------------
__global__ __launch_bounds__(512, 4) void nfloop_kernel(
    const float* __restrict__ node_ft, const float* __restrict__ w_bias,
    float* __restrict__ out, int N) {
    __shared__ char smem[32768];
    unsigned short* A = (unsigned short*)smem;
    const int t = threadIdx.x;
    const int wv = t >> 6;
    const long long r0 = (long long)blockIdx.x * 64;
    {
        float4 stg[8];
#pragma unroll
        for (int q = 0; q < 8; ++q) {
            int idx = q * 512 + t;
            long long gr = r0 + (idx >> 6);
            if (gr >= N) gr = N - 1;
            stg[q] = ((const float4*)node_ft)[gr * 64 + (idx & 63)];
        }
        // Nyquist: NF[:,256] = sum_k (-1)^k x_k  (k = 4*(t&63) even -> +x-y+z-w)
#pragma unroll
        for (int q = 0; q < 8; ++q) {
            float c = stg[q].x - stg[q].y + stg[q].z - stg[q].w;
            c = waveSum(c);
            int row = q * 8 + wv;
            if ((t & 63) == 0 && r0 + row < N)
                g_NF[(r0 + row) * NFW + 256] = (_Float16)c;
        }
        stage_write(smem, stg, t);
    }
    __syncthreads();

    const int lane = t & 63;
    const int mw = wv >> 2, nw = wv & 3;
    const int l15 = lane & 15, lg = lane >> 4;

    // GEMM-F: tiles tn = nw + 4j (16 tiles, uniform)
    {
        f32x4 acc[2][4] = {};
#pragma unroll
        for (int ks = 0; ks < 8; ++ks) {
            half8 a0 = *(const half8*)((char*)A + ((2 * mw + 0) * 8 + ks) * 1024 + ((lane * 16) ^ (ks << 4)));
            half8 a1 = *(const half8*)((char*)A + ((2 * mw + 1) * 8 + ks) * 1024 + ((lane * 16) ^ (ks << 4)));
#pragma unroll
            for (int j = 0; j < 4; ++j) {
                int tn = nw + 4 * j;
                half8 bf = *(const half8*)(g_FB + ((size_t)(ks * 20 + tn) * 64 + lane) * 8);
                acc[0][j] = MFMA16F(a0, bf, acc[0][j], 0, 0, 0);
                acc[1][j] = MFMA16F(a1, bf, acc[1][j], 0, 0, 0);
            }
        }
#pragma unroll
        for (int mt = 0; mt < 2; ++mt)
#pragma unroll
            for (int j = 0; j < 4; ++j) {
                int r2 = (nw + 4 * j) * 16 + l15;
#pragma unroll
                for (int r = 0; r < 4; ++r) {
                    long long gr = r0 + (2 * mw + mt) * 16 + lg * 4 + r;
                    if (gr < N) g_NF[gr * NFW + r2] = (_Float16)acc[mt][j][r];
                }
            }
    }
    // GEMM-W: write loop_msg + bias into d_out
    {
        f32x4 acc[2][4] = {};
#pragma unroll
        for (int ks = 0; ks < 8; ++ks) {
            half8 a0 = *(const half8*)((char*)A + ((2 * mw + 0) * 8 + ks) * 1024 + ((lane * 16) ^ (ks << 4)));
            half8 a1 = *(const half8*)((char*)A + ((2 * mw + 1) * 8 + ks) * 1024 + ((lane * 16) ^ (ks << 4)));
#pragma unroll
            for (int j = 0; j < 4; ++j) {
                half8 bf = *(const half8*)(g_WLEB + ((size_t)(ks * 16 + 4 * nw + j) * 64 + lane) * 8);
                acc[0][j] = MFMA16F(a0, bf, acc[0][j], 0, 0, 0);
                acc[1][j] = MFMA16F(a1, bf, acc[1][j], 0, 0, 0);
            }
        }
#pragma unroll
        for (int j = 0; j < 4; ++j) {
            const int col = (4 * nw + j) * 16 + l15;
            const float bj = w_bias[col];
#pragma unroll
            for (int mt = 0; mt < 2; ++mt)
#pragma unroll
                for (int r = 0; r < 4; ++r) {
                    long long gr = r0 + (2 * mw + mt) * 16 + lg * 4 + r;
                    if (gr < N)
                        out[gr * 256 + col] = acc[mt][j][r] + bj;
                }
        }
    }
}

// ---------------------------------------------------------------------------
// edge kernel: 64 dst-sorted edges/block. EF = y@F (16 tiles) -> Z =
// conj(NF[src])*EF (fp16, A-frag alias) -> msg = Z@Chat (K=256) + Nyquist
// rank-1 -> norm-scaled compressed atomic scatter into d_out.
// ---------------------------------------------------------------------------
__global__ __launch_bounds__(512, 6) void edge_kernel(
    const float* __restrict__ edge_ft, const float* __restrict__ norm,
    const int* __restrict__ src, const int* __restrict__ dst,
    float* __restrict__ agg, int E) {
    __shared__ char smem[32768 + 1024];
    unsigned short* A = (unsigned short*)smem;
    unsigned short* Z = (unsigned short*)smem;       // alias (barrier-guarded)
    int*   sdd  = (int*)(smem + 32768);              // 64 dsts
    float* snrm = (float*)(smem + 32768 + 256);      // 64 norms
    int*   ssrc = (int*)(smem + 32768 + 512);        // 64 srcs
    float* nyq  = (float*)(smem + 32768 + 768);      // EF nyquist -> Z nyquist

    const int t = threadIdx.x;
    const long long ebase = (long long)blockIdx.x * 64;
    const int lane = t & 63, wv = t >> 6;
    const int mw = wv >> 2, nw = wv & 3;
    const int l15 = lane & 15, lg = lane >> 4;
    const bool odd = (l15 & 1);

    if (t < 64) {
        long long ge = ebase + t;
        if (ge >= E) ge = E - 1;
        int p = g_perm[ge];
        int d = dst[p];
        sdd[t] = d;
        snrm[t] = norm[d];
        ssrc[t] = src[p];
    }

    // stage edge rows (perm gather; each row 1KB coalesced) + Nyquist alt-sum
    {
        float4 stg[8];
#pragma unroll
        for (int q = 0; q < 8; ++q) {
            long long ge = ebase + q * 8 + wv;
            if (ge >= E) ge = E - 1;
            stg[q] = ((const float4*)edge_ft)[(long long)g_perm[ge] * 64 + lane];
        }
#pragma unroll
        for (int q = 0; q < 8; ++q) {
            float c = stg[q].x - stg[q].y + stg[q].z - stg[q].w;
            c = waveSum(c);
            if (lane == 0) nyq[q * 8 + wv] = c;
        }
        stage_write(smem, stg, t);
    }
    __syncthreads();

    // GEMM1: EF tiles tn = nw + 4j (16 tiles, uniform)
    f32x4 acc1[2][4] = {};
#pragma unroll
    for (int ks = 0; ks < 8; ++ks) {
        half8 a0 = *(const half8*)((char*)A + ((2 * mw + 0) * 8 + ks) * 1024 + ((lane * 16) ^ (ks << 4)));
        half8 a1 = *(const half8*)((char*)A + ((2 * mw + 1) * 8 + ks) * 1024 + ((lane * 16) ^ (ks << 4)));
#pragma unroll
        for (int j = 0; j < 4; ++j) {
            int tn = nw + 4 * j;
            half8 bf = *(const half8*)(g_FB + ((size_t)(ks * 20 + tn) * 64 + lane) * 8);
            acc1[0][j] = MFMA16F(a0, bf, acc1[0][j], 0, 0, 0);
            acc1[1][j] = MFMA16F(a1, bf, acc1[1][j], 0, 0, 0);
        }
    }
    __syncthreads();  // A reads done; Z may overwrite

    // Z nyquist: Znyq[e] = EFnyq[e] * NFnyq[src[e]]  (in-place over nyq)
    if (t < 64)
        nyq[t] = nyq[t] * (float)g_NF[(size_t)ssrc[t] * NFW + 256];

    // Hadamard: Z = conj(NF[src]) * EF, fp16 into A-frag layout (8 chunks)
#pragma unroll
    for (int mt = 0; mt < 2; ++mt) {
        int tm = 2 * mw + mt;
#pragma unroll
        for (int r = 0; r < 4; ++r) {
            int e = tm * 16 + lg * 4 + r;
            const char* nfrow = (const char*)(g_NF + (size_t)ssrc[e] * NFW);
#pragma unroll
            for (int j = 0; j < 4; ++j) {
                int r2 = (nw + 4 * j) * 16 + l15;
                float own = acc1[mt][j][r];
                float oth = __shfl_xor(own, 1);
                union { unsigned int u; half2v h; } cv;
                cv.u = *(const unsigned int*)(nfrow + (r2 & ~1) * 2);
                float br = (float)cv.h[0], bi = (float)cv.h[1];
                float z = odd ? (br * own - bi * oth) : (br * own + bi * oth);
                int ksz = r2 >> 5;
                int off = (tm * 8 + ksz) * 1024 +
                          ((((((r2 >> 3) & 3) << 4) | (e & 15)) * 16) ^ (ksz << 4)) +
                          (r2 & 7) * 2;
                *(unsigned short*)((char*)Z + off) = f2hu(z);
            }
        }
    }
    __syncthreads();

    // GEMM2: msg = Z @ Chat (K = 256) + Nyquist rank-1
    f32x4 acc2[2][4] = {};
#pragma unroll
    for (int ks = 0; ks < 8; ++ks) {
        half8 a0 = *(const half8*)((char*)Z + ((2 * mw + 0) * 8 + ks) * 1024 + ((lane * 16) ^ (ks << 4)));
        half8 a1 = *(const half8*)((char*)Z + ((2 * mw + 1) * 8 + ks) * 1024 + ((lane * 16) ^ (ks << 4)));
#pragma unroll
        for (int j = 0; j < 4; ++j) {
            half8 bf = *(const half8*)(g_CB + ((size_t)(ks * 16 + 4 * nw + j) * 64 + lane) * 8);
            acc2[0][j] = MFMA16F(a0, bf, acc2[0][j], 0, 0, 0);
            acc2[1][j] = MFMA16F(a1, bf, acc2[1][j], 0, 0, 0);
        }
    }
    {
        float c256[4];
#pragma unroll
        for (int j = 0; j < 4; ++j) c256[j] = g_C256[(4 * nw + j) * 16 + l15];
#pragma unroll
        for (int mt = 0; mt < 2; ++mt)
#pragma unroll
            for (int r = 0; r < 4; ++r) {
                float zn = nyq[(2 * mw + mt) * 16 + lg * 4 + r];
#pragma unroll
                for (int j = 0; j < 4; ++j)
                    acc2[mt][j][r] = fmaf(zn, c256[j], acc2[mt][j][r]);
            }
    }

    // scatter: norm-scaled, dst-run compressed (sorted order)
#pragma unroll
    for (int mt = 0; mt < 2; ++mt) {
        const int e0 = (2 * mw + mt) * 16 + lg * 4;
        const bool v0 = ebase + e0 < E, v1 = ebase + e0 + 1 < E;
        const bool v2 = ebase + e0 + 2 < E, v3 = ebase + e0 + 3 < E;
        const int d0 = sdd[e0], d1 = sdd[e0 + 1], d2 = sdd[e0 + 2], d3 = sdd[e0 + 3];
        const float n0 = snrm[e0], n1 = snrm[e0 + 1], n2 = snrm[e0 + 2], n3 = snrm[e0 + 3];
        const bool uni = v3 && (d0 == d1) && (d1 == d2) && (d2 == d3);
        const bool p01 = v1 && (d0 == d1);
        const bool p23 = v3 && (d2 == d3);
#pragma unroll
        for (int j = 0; j < 4; ++j) {
            const int col = (4 * nw + j) * 16 + l15;
            float x0 = acc2[mt][j][0] * n0, x1 = acc2[mt][j][1] * n1;
            float x2 = acc2[mt][j][2] * n2, x3 = acc2[mt][j][3] * n3;
            if (uni) {
                atomAddF(agg + (long long)d0 * 256 + col, (x0 + x1) + (x2 + x3));
            } else {
                if (p01) atomAddF(agg + (long long)d0 * 256 + col, x0 + x1);
                else {
                    if (v0) atomAddF(agg + (long long)d0 * 256 + col, x0);
                    if (v1) atomAddF(agg + (long long)d1 * 256 + col, x1);
                }
                if (p23) atomAddF(agg + (long long)d2 * 256 + col, x2 + x3);
                else {
                    if (v2) atomAddF(agg + (long long)d2 * 256 + col, x2);
                    if (v3) atomAddF(agg + (long long)d3 * 256 + col, x3);
                }
            }
        }
    }
}

// ---------------------------------------------------------------------------
// stats: per-column sum / sumsq of h (= d_out) for BN
// ---------------------------------------------------------------------------
__global__ __launch_bounds__(256) void stats_kernel(
    const float* __restrict__ h, float* __restrict__ s1g,
    float* __restrict__ s2g, long long tot4) {
    __shared__ float s1l[256], s2l[256];
    const int t = threadIdx.x;
    s1l[t] = 0.f;
    s2l[t] = 0.f;
    __syncthreads();
    const int dg = t & 63;
    float a1[4] = {0.f, 0.f, 0.f, 0.f}, a2[4] = {0.f, 0.f, 0.f, 0.f};
    const long long stride = (long long)gridDim.x * 256;
    for (long long i4 = (long long)blockIdx.x * 256 + t; i4 < tot4; i4 += stride) {
        float4 v = ((const float4*)h)[i4];
        a1[0] += v.x; a2[0] += v.x * v.x;
        a1[1] += v.y; a2[1] += v.y * v.y;
        a1[2] += v.z; a2[2] += v.z * v.z;
        a1[3] += v.w; a2[3] += v.w * v.w;
    }
#pragma unroll
    for (int c = 0; c < 4; ++c) {
        atomicAdd(&s1l[dg * 4 + c], a1[c]);
        atomicAdd(&s2l[dg * 4 + c], a2[c]);
    }
    __syncthreads();
    atomAddF(&s1g[t], s1l[t]);
    atomAddF(&s2g[t], s2l[t]);
}

// ---------------------------------------------------------------------------
// finalize: out = tanh((h - mean) * rsqrt(var + eps) * gamma + beta)
// ---------------------------------------------------------------------------
__global__ __launch_bounds__(256) void finalize_kernel(
    float* __restrict__ out, const float* __restrict__ s1g,
    const float* __restrict__ s2g, const float* __restrict__ gamma,
    const float* __restrict__ beta, int N) {
    long long i4 = (long long)blockIdx.x * blockDim.x + threadIdx.x;
    long long tot = (long long)N * 64;
    if (i4 >= tot) return;
    const int dg = (int)(i4 & 63);
    float4 h = ((float4*)out)[i4];
    const float4 s1 = ((const float4*)s1g)[dg];
    const float4 s2 = ((const float4*)s2g)[dg];
    const float4 g = ((const float4*)gamma)[dg];
    const float4 b = ((const float4*)beta)[dg];
    const float invN = 1.f / (float)N;
    float4 o;
    { float m = s1.x * invN; float v = s2.x * invN - m * m;
      o.x = tanhf(fmaf(h.x - m, rsqrtf(v + BN_EPS) * g.x, b.x)); }
    { float m = s1.y * invN; float v = s2.y * invN - m * m;
      o.y = tanhf(fmaf(h.y - m, rsqrtf(v + BN_EPS) * g.y, b.y)); }
    { float m = s1.z * invN; float v = s2.z * invN - m * m;
      o.z = tanhf(fmaf(h.z - m, rsqrtf(v + BN_EPS) * g.z, b.z)); }
    { float m = s1.w * invN; float v = s2.w * invN - m * m;
      o.w = tanhf(fmaf(h.w - m, rsqrtf(v + BN_EPS) * g.w, b.w)); }
    ((float4*)out)[i4] = o;
}

// ---------------------------------------------------------------------------
extern "C" void kernel_launch(void* const* d_in, const int* in_sizes, int n_in,
                              void* d_out, int out_size, void* d_ws, size_t ws_size,
                              hipStream_t stream) {
    const float* node_ft  = (const float*)d_in[0];
    const float* edge_ft  = (const float*)d_in[1];
    const float* norm     = (const float*)d_in[2];
    const float* w_loop   = (const float*)d_in[3];
    const float* w_in     = (const float*)d_in[4];
    const float* loop_rel = (const float*)d_in[5];
    const float* w_bias   = (const float*)d_in[6];
    const float* bn_gamma = (const float*)d_in[7];
    const float* bn_beta  = (const float*)d_in[8];
    const int*   src      = (const int*)d_in[9];
    const int*   dst      = (const int*)d_in[10];

    const int N = in_sizes[2];
    const int E = in_sizes[9];
    float* out = (float*)d_out;

    float* s1g = (float*)d_ws;
    float* s2g = s1g + 256;

    hipMemsetAsync(d_ws, 0, 512 * sizeof(float), stream);

    float* Wle_ptr = nullptr;
    hipGetSymbolAddress((void**)&Wle_ptr, HIP_SYMBOL(g_Wle));
    void* hist_ptr = nullptr;
    hipGetSymbolAddress(&hist_ptr, HIP_SYMBOL(g_hist));
    hipMemsetAsync(hist_ptr, 0, (size_t)N * sizeof(int), stream);

    const int sblk = (N + 511) / 512;
    const int eblk = (E + 511) / 512;

    // dst counting sort -> g_perm (+ g_off segments, unused here but cheap)
    hist_kernel<<<eblk, 512, 0, stream>>>(dst, E);
    scanA_kernel<<<sblk, 512, 0, stream>>>(N);
    scanB_kernel<<<1, 128, 0, stream>>>(sblk);
    scanC_kernel<<<sblk, 512, 0, stream>>>(N);
    perm_kernel<<<eblk, 512, 0, stream>>>(dst, E);

    // constant packs
    wle_kernel<<<256, 256, 0, stream>>>(loop_rel, w_loop, Wle_ptr);
    fb_pack<<<8 * 20, 512, 0, stream>>>();
    cb_pack<<<9 * 16, 512, 0, stream>>>(w_in);
    wleb_pack<<<8 * 16, 512, 0, stream>>>();

    // node pass -> NF + (loop_msg + bias) in d_out
    nfloop_kernel<<<(N + 63) / 64, 512, 0, stream>>>(node_ft, w_bias, out, N);
    // fused edge pass: compute + norm-scaled compressed atomic scatter
    edge_kernel<<<(E + 63) / 64, 512, 0, stream>>>(edge_ft, norm, src, dst, out, E);
    stats_kernel<<<256, 256, 0, stream>>>(out, s1g, s2g, (long long)N * 64);
    finalize_kernel<<<(int)(((long long)N * 64 + 255) / 256), 256, 0, stream>>>(
        out, s1g, s2g, bn_gamma, bn_beta, N);
}

// Round 11
// 430.425 us; speedup vs baseline: 1.3561x; 1.0588x over previous
//
#include <hip/hip_runtime.h>
#include <hip/hip_bf16.h>

#define NN 50000
#define EE 300000
#define BN_EPS 1e-5f
#define NFW 288            // NF row stride in fp16 elems
#define TWOPI_256 0.024543692606170259f  // 2*pi/256
#define NXCD 8

typedef __attribute__((ext_vector_type(8))) _Float16 half8;
typedef __attribute__((ext_vector_type(2))) _Float16 half2v;
typedef __attribute__((ext_vector_type(4))) float f32x4;
#define MFMA16F __builtin_amdgcn_mfma_f32_16x16x32_f16

// ---- static device scratch ----
__device__ __align__(16) _Float16 g_NF[(size_t)NN * NFW];  // node rfft table, fp16
__device__ float g_Wle[256 * 256];                         // folded loop matrix, fp32
__device__ float g_C256[256];                              // Chat row 256 (Nyquist), fp32
// B operands pre-swizzled into MFMA fragment order: [ks][ntile][lane][8]
__device__ __align__(16) unsigned short g_FB[8 * 20 * 64 * 8];   // rfft matrix F
__device__ __align__(16) unsigned short g_CB[9 * 16 * 64 * 8];   // Chat
__device__ __align__(16) unsigned short g_WLEB[8 * 16 * 64 * 8]; // W_le
// dst counting-sort scratch
__device__ int g_hist[NN];
__device__ int g_off[NN + 1];
__device__ int g_cursor[NN];
__device__ int g_perm[EE];
__device__ int g_bsum[128];
__device__ int g_bbase[128];

__device__ __forceinline__ void atomAddF(float* p, float v) { unsafeAtomicAdd(p, v); }

__device__ __forceinline__ unsigned short f2hu(float x) {
    union { _Float16 f; unsigned short u; } c;
    c.f = (_Float16)x;
    return c.u;
}

// ---------------------------------------------------------------------------
// staged fp32 regs -> fp16 MFMA A-fragments in LDS (XOR-swizzled), 8 chunks.
// lane l of tile m, kstep ks holds A[m*16+(l&15)][32*ks+8*(l>>4)+e].
// ---------------------------------------------------------------------------
__device__ __forceinline__ void stage_write(char* A, const float4* stg, int t) {
#pragma unroll
    for (int q = 0; q < 8; ++q) {
        int idx = q * 512 + t;
        int row = idx >> 6, c4 = idx & 63;
        union { _Float16 f[4]; ushort4 u; } r;
        r.f[0] = (_Float16)stg[q].x; r.f[1] = (_Float16)stg[q].y;
        r.f[2] = (_Float16)stg[q].z; r.f[3] = (_Float16)stg[q].w;
        int ks = c4 >> 3;
        int off = ((row >> 4) * 8 + ks) * 1024 +
                  ((((((c4 >> 1) & 3) << 4) | (row & 15)) * 16) ^ (ks << 4)) +
                  (c4 & 1) * 8;
        *(ushort4*)(A + off) = r.u;
    }
}

// full-wave sum of v across 64 lanes
__device__ __forceinline__ float waveSum(float v) {
#pragma unroll
    for (int d = 1; d < 64; d <<= 1) v += __shfl_xor(v, d);
    return v;
}

// ---------------------------------------------------------------------------
// dst counting sort: hist -> 2-level exclusive scan -> permutation
// ---------------------------------------------------------------------------
__global__ __launch_bounds__(512) void hist_kernel(const int* __restrict__ dst, int E) {
    int e = blockIdx.x * 512 + threadIdx.x;
    if (e < E) atomicAdd(&g_hist[dst[e]], 1);
}

__global__ __launch_bounds__(512) void scanA_kernel(int N) {
    __shared__ int arr[512];
    int t = threadIdx.x, b = blockIdx.x * 512 + t;
    int cnt = (b < N) ? g_hist[b] : 0;
    arr[t] = cnt;
    __syncthreads();
#pragma unroll
    for (int off = 1; off < 512; off <<= 1) {
        int v = (t >= off) ? arr[t - off] : 0;
        __syncthreads();
        arr[t] += v;
        __syncthreads();
    }
    if (b < N) g_off[b] = arr[t] - cnt;
    if (t == 511) g_bsum[blockIdx.x] = arr[511];
}

__global__ __launch_bounds__(128) void scanB_kernel(int nblk) {
    __shared__ int arr[128];
    int t = threadIdx.x;
    int v0 = (t < nblk) ? g_bsum[t] : 0;
    arr[t] = v0;
    __syncthreads();
#pragma unroll
    for (int off = 1; off < 128; off <<= 1) {
        int v = (t >= off) ? arr[t - off] : 0;
        __syncthreads();
        arr[t] += v;
        __syncthreads();
    }
    if (t < nblk) g_bbase[t] = arr[t] - v0;
}

__global__ __launch_bounds__(512) void scanC_kernel(int N) {
    int b = blockIdx.x * 512 + threadIdx.x;
    if (b < N) {
        int v = g_off[b] + g_bbase[blockIdx.x];
        g_off[b] = v;
        g_cursor[b] = v;
        if (b == N - 1) g_off[N] = v + g_hist[b];
    }
}

__global__ __launch_bounds__(512) void perm_kernel(const int* __restrict__ dst, int E) {
    int e = blockIdx.x * 512 + threadIdx.x;
    if (e < E) {
        int pos = atomicAdd(&g_cursor[dst[e]], 1);
        g_perm[pos] = e;
    }
}

// ---------------------------------------------------------------------------
// K1: W_le[j][d] = sum_k loop_rel[(j+k)%256] * w_loop[k][d]
// ---------------------------------------------------------------------------
__global__ __launch_bounds__(256) void wle_kernel(
    const float* __restrict__ loop_rel, const float* __restrict__ w_loop,
    float* __restrict__ W_le) {
    __shared__ float lr[256];
    const int d = threadIdx.x, j = blockIdx.x;
    lr[d] = loop_rel[d];
    __syncthreads();
    float acc = 0.f;
#pragma unroll 4
    for (int k = 0; k < 256; ++k)
        acc = fmaf(lr[(j + k) & 255], w_loop[k * 256 + d], acc);
    W_le[j * 256 + d] = acc;
}

// ---------------------------------------------------------------------------
// pack F into B-fragment order, fp16
// ---------------------------------------------------------------------------
__global__ __launch_bounds__(512) void fb_pack() {
    int b = blockIdx.x, ks = b / 20, nt = b % 20;
    int t = threadIdx.x, lane = t >> 3, e = t & 7;
    int k = 32 * ks + 8 * (lane >> 4) + e;
    int r2 = nt * 16 + (lane & 15);
    float val = 0.f;
    if (r2 < 258) {
        int f = r2 >> 1;
        int m = (f * k) & 255;
        float s, c;
        sincosf((float)m * TWOPI_256, &s, &c);
        val = (r2 & 1) ? -s : c;
    }
    g_FB[((ks * 20 + nt) * 64 + lane) * 8 + e] = f2hu(val);
}

// ---------------------------------------------------------------------------
// pack Chat into B-fragment order, fp16; also emit fp32 row 256 -> g_C256.
// ---------------------------------------------------------------------------
__global__ __launch_bounds__(512) void cb_pack(const float* __restrict__ w_in) {
    __shared__ float ct[256], st[256];
    int t = threadIdx.x;
    if (t < 256) {
        float s, c;
        sincosf((float)t * TWOPI_256, &s, &c);
        ct[t] = c; st[t] = s;
    }
    __syncthreads();
    int b = blockIdx.x, ks = b / 16, nt = b % 16;
    int lane = t >> 3, e = t & 7;
    int kk = 32 * ks + 8 * (lane >> 4) + e;
    int d = nt * 16 + (lane & 15);
    float val = 0.f;
    if (kk < 258) {
        int f = kk >> 1;
        float cf = (f == 0 || f == 128) ? (1.f / 256.f) : (2.f / 256.f);
        const float* tab = (kk & 1) ? st : ct;
        float sgn = (kk & 1) ? -1.f : 1.f;
        float acc = 0.f;
        for (int k = 0; k < 256; ++k)
            acc = fmaf(tab[(f * k) & 255], w_in[k * 256 + d], acc);
        val = cf * sgn * acc;
    }
    if (kk == 256) g_C256[d] = val;   // Nyquist row, fp32
    g_CB[((ks * 16 + nt) * 64 + lane) * 8 + e] = f2hu(val);
}

// pack W_le into B-fragment order, fp16.
__global__ __launch_bounds__(512) void wleb_pack() {
    int b = blockIdx.x, ks = b / 16, nt = b % 16;
    int t = threadIdx.x, lane = t >> 3, e = t & 7;
    int k = 32 * ks + 8 * (lane >> 4) + e;
    int d = nt * 16 + (lane & 15);
    g_WLEB[((ks * 16 + nt) * 64 + lane) * 8 + e] = f2hu(g_Wle[k * 256 + d]);
}

// ---------------------------------------------------------------------------
// nfloop: per 64 node rows: NF = node @ F (cols 0..255 via MFMA; col 256 =
// alternating sum via wave-reduce during staging), d_out = node @ W_le + bias.
// ---------------------------------------------------------------------------
__global__ __launch_bounds__(512, 4) void nfloop_kernel(
    const float* __restrict__ node_ft, const float* __restrict__ w_bias,
    float* __restrict__ out, int N) {
    __shared__ char smem[32768];
    unsigned short* A = (unsigned short*)smem;
    const int t = threadIdx.x;
    const int wv = t >> 6;
    const long long r0 = (long long)blockIdx.x * 64;
    {
        float4 stg[8];
#pragma unroll
        for (int q = 0; q < 8; ++q) {
            int idx = q * 512 + t;
            long long gr = r0 + (idx >> 6);
            if (gr >= N) gr = N - 1;
            stg[q] = ((const float4*)node_ft)[gr * 64 + (idx & 63)];
        }
#pragma unroll
        for (int q = 0; q < 8; ++q) {
            float c = stg[q].x - stg[q].y + stg[q].z - stg[q].w;
            c = waveSum(c);
            int row = q * 8 + wv;
            if ((t & 63) == 0 && r0 + row < N)
                g_NF[(r0 + row) * NFW + 256] = (_Float16)c;
        }
        stage_write(smem, stg, t);
    }
    __syncthreads();

    const int lane = t & 63;
    const int mw = wv >> 2, nw = wv & 3;
    const int l15 = lane & 15, lg = lane >> 4;

    // GEMM-F: tiles tn = nw + 4j (16 tiles, uniform)
    {
        f32x4 acc[2][4] = {};
#pragma unroll
        for (int ks = 0; ks < 8; ++ks) {
            half8 a0 = *(const half8*)((char*)A + ((2 * mw + 0) * 8 + ks) * 1024 + ((lane * 16) ^ (ks << 4)));
            half8 a1 = *(const half8*)((char*)A + ((2 * mw + 1) * 8 + ks) * 1024 + ((lane * 16) ^ (ks << 4)));
#pragma unroll
            for (int j = 0; j < 4; ++j) {
                int tn = nw + 4 * j;
                half8 bf = *(const half8*)(g_FB + ((size_t)(ks * 20 + tn) * 64 + lane) * 8);
                acc[0][j] = MFMA16F(a0, bf, acc[0][j], 0, 0, 0);
                acc[1][j] = MFMA16F(a1, bf, acc[1][j], 0, 0, 0);
            }
        }
#pragma unroll
        for (int mt = 0; mt < 2; ++mt)
#pragma unroll
            for (int j = 0; j < 4; ++j) {
                int r2 = (nw + 4 * j) * 16 + l15;
#pragma unroll
                for (int r = 0; r < 4; ++r) {
                    long long gr = r0 + (2 * mw + mt) * 16 + lg * 4 + r;
                    if (gr < N) g_NF[gr * NFW + r2] = (_Float16)acc[mt][j][r];
                }
            }
    }
    // GEMM-W: write loop_msg + bias into d_out
    {
        f32x4 acc[2][4] = {};
#pragma unroll
        for (int ks = 0; ks < 8; ++ks) {
            half8 a0 = *(const half8*)((char*)A + ((2 * mw + 0) * 8 + ks) * 1024 + ((lane * 16) ^ (ks << 4)));
            half8 a1 = *(const half8*)((char*)A + ((2 * mw + 1) * 8 + ks) * 1024 + ((lane * 16) ^ (ks << 4)));
#pragma unroll
            for (int j = 0; j < 4; ++j) {
                half8 bf = *(const half8*)(g_WLEB + ((size_t)(ks * 16 + 4 * nw + j) * 64 + lane) * 8);
                acc[0][j] = MFMA16F(a0, bf, acc[0][j], 0, 0, 0);
                acc[1][j] = MFMA16F(a1, bf, acc[1][j], 0, 0, 0);
            }
        }
#pragma unroll
        for (int j = 0; j < 4; ++j) {
            const int col = (4 * nw + j) * 16 + l15;
            const float bj = w_bias[col];
#pragma unroll
            for (int mt = 0; mt < 2; ++mt)
#pragma unroll
                for (int r = 0; r < 4; ++r) {
                    long long gr = r0 + (2 * mw + mt) * 16 + lg * 4 + r;
                    if (gr < N)
                        out[gr * 256 + col] = acc[mt][j][r] + bj;
                }
        }
    }
}

// ---------------------------------------------------------------------------
// edge kernel: 64 dst-sorted edges/block, XCD-chunked tile assignment so each
// XCD's L2 owns a contiguous dst range (atomic lines written back ~once).
// EF = y@F -> Z = conj(NF[src])*EF -> msg = Z@Chat + Nyquist rank-1
// -> norm-scaled compressed atomic scatter into d_out.
// ---------------------------------------------------------------------------
__global__ __launch_bounds__(512, 4) void edge_kernel(
    const float* __restrict__ edge_ft, const float* __restrict__ norm,
    const int* __restrict__ src, const int* __restrict__ dst,
    float* __restrict__ agg, int E) {
    __shared__ char smem[32768 + 1024];
    unsigned short* A = (unsigned short*)smem;
    unsigned short* Z = (unsigned short*)smem;       // alias (barrier-guarded)
    int*   sdd  = (int*)(smem + 32768);              // 64 dsts
    float* snrm = (float*)(smem + 32768 + 256);      // 64 norms
    int*   ssrc = (int*)(smem + 32768 + 512);        // 64 srcs
    float* nyq  = (float*)(smem + 32768 + 768);      // EF nyquist -> Z nyquist

    // bijective XCD-chunked remap (m204): hardware round-robins blockIdx
    // across XCDs; give XCD k a CONTIGUOUS range of dst-sorted tiles.
    const int nwg = gridDim.x;
    const int q = nwg >> 3, r = nwg & 7;
    const int xcd = blockIdx.x & 7, idx = blockIdx.x >> 3;
    const int tile = (xcd < r ? xcd * (q + 1) : r * (q + 1) + (xcd - r) * q) + idx;

    const int t = threadIdx.x;
    const long long ebase = (long long)tile * 64;
    const int lane = t & 63, wv = t >> 6;
    const int mw = wv >> 2, nw = wv & 3;
    const int l15 = lane & 15, lg = lane >> 4;
    const bool odd = (l15 & 1);

    if (t < 64) {
        long long ge = ebase + t;
        if (ge >= E) ge = E - 1;
        int p = g_perm[ge];
        int d = dst[p];
        sdd[t] = d;
        snrm[t] = norm[d];
        ssrc[t] = src[p];
    }

    // stage edge rows (perm gather; each row 1KB coalesced) + Nyquist alt-sum
    {
        float4 stg[8];
#pragma unroll
        for (int q2 = 0; q2 < 8; ++q2) {
            long long ge = ebase + q2 * 8 + wv;
            if (ge >= E) ge = E - 1;
            stg[q2] = ((const float4*)edge_ft)[(long long)g_perm[ge] * 64 + lane];
        }
#pragma unroll
        for (int q2 = 0; q2 < 8; ++q2) {
            float c = stg[q2].x - stg[q2].y + stg[q2].z - stg[q2].w;
            c = waveSum(c);
            if (lane == 0) nyq[q2 * 8 + wv] = c;
        }
        stage_write(smem, stg, t);
    }
    __syncthreads();

    // GEMM1: EF tiles tn = nw + 4j (16 tiles, uniform)
    f32x4 acc1[2][4] = {};
#pragma unroll
    for (int ks = 0; ks < 8; ++ks) {
        half8 a0 = *(const half8*)((char*)A + ((2 * mw + 0) * 8 + ks) * 1024 + ((lane * 16) ^ (ks << 4)));
        half8 a1 = *(const half8*)((char*)A + ((2 * mw + 1) * 8 + ks) * 1024 + ((lane * 16) ^ (ks << 4)));
#pragma unroll
        for (int j = 0; j < 4; ++j) {
            int tn = nw + 4 * j;
            half8 bf = *(const half8*)(g_FB + ((size_t)(ks * 20 + tn) * 64 + lane) * 8);
            acc1[0][j] = MFMA16F(a0, bf, acc1[0][j], 0, 0, 0);
            acc1[1][j] = MFMA16F(a1, bf, acc1[1][j], 0, 0, 0);
        }
    }
    __syncthreads();  // A reads done; Z may overwrite

    // Z nyquist: Znyq[e] = EFnyq[e] * NFnyq[src[e]]
    if (t < 64)
        nyq[t] = nyq[t] * (float)g_NF[(size_t)ssrc[t] * NFW + 256];

    // Hadamard: Z = conj(NF[src]) * EF, fp16 into A-frag layout (8 chunks)
#pragma unroll
    for (int mt = 0; mt < 2; ++mt) {
        int tm = 2 * mw + mt;
#pragma unroll
        for (int r2i = 0; r2i < 4; ++r2i) {
            int e = tm * 16 + lg * 4 + r2i;
            const char* nfrow = (const char*)(g_NF + (size_t)ssrc[e] * NFW);
#pragma unroll
            for (int j = 0; j < 4; ++j) {
                int r2 = (nw + 4 * j) * 16 + l15;
                float own = acc1[mt][j][r2i];
                float oth = __shfl_xor(own, 1);
                union { unsigned int u; half2v h; } cv;
                cv.u = *(const unsigned int*)(nfrow + (r2 & ~1) * 2);
                float br = (float)cv.h[0], bi = (float)cv.h[1];
                float z = odd ? (br * own - bi * oth) : (br * own + bi * oth);
                int ksz = r2 >> 5;
                int off = (tm * 8 + ksz) * 1024 +
                          ((((((r2 >> 3) & 3) << 4) | (e & 15)) * 16) ^ (ksz << 4)) +
                          (r2 & 7) * 2;
                *(unsigned short*)((char*)Z + off) = f2hu(z);
            }
        }
    }
    __syncthreads();

    // GEMM2: msg = Z @ Chat (K = 256) + Nyquist rank-1
    f32x4 acc2[2][4] = {};
#pragma unroll
    for (int ks = 0; ks < 8; ++ks) {
        half8 a0 = *(const half8*)((char*)Z + ((2 * mw + 0) * 8 + ks) * 1024 + ((lane * 16) ^ (ks << 4)));
        half8 a1 = *(const half8*)((char*)Z + ((2 * mw + 1) * 8 + ks) * 1024 + ((lane * 16) ^ (ks << 4)));
#pragma unroll
        for (int j = 0; j < 4; ++j) {
            half8 bf = *(const half8*)(g_CB + ((size_t)(ks * 16 + 4 * nw + j) * 64 + lane) * 8);
            acc2[0][j] = MFMA16F(a0, bf, acc2[0][j], 0, 0, 0);
            acc2[1][j] = MFMA16F(a1, bf, acc2[1][j], 0, 0, 0);
        }
    }
    {
        float c256[4];
#pragma unroll
        for (int j = 0; j < 4; ++j) c256[j] = g_C256[(4 * nw + j) * 16 + l15];
#pragma unroll
        for (int mt = 0; mt < 2; ++mt)
#pragma unroll
            for (int r2i = 0; r2i < 4; ++r2i) {
                float zn = nyq[(2 * mw + mt) * 16 + lg * 4 + r2i];
#pragma unroll
                for (int j = 0; j < 4; ++j)
                    acc2[mt][j][r2i] = fmaf(zn, c256[j], acc2[mt][j][r2i]);
            }
    }

    // scatter: norm-scaled, dst-run compressed (sorted order)
#pragma unroll
    for (int mt = 0; mt < 2; ++mt) {
        const int e0 = (2 * mw + mt) * 16 + lg * 4;
        const bool v0 = ebase + e0 < E, v1 = ebase + e0 + 1 < E;
        const bool v2 = ebase + e0 + 2 < E, v3 = ebase + e0 + 3 < E;
        const int d0 = sdd[e0], d1 = sdd[e0 + 1], d2 = sdd[e0 + 2], d3 = sdd[e0 + 3];
        const float n0 = snrm[e0], n1 = snrm[e0 + 1], n2 = snrm[e0 + 2], n3 = snrm[e0 + 3];
        const bool uni = v3 && (d0 == d1) && (d1 == d2) && (d2 == d3);
        const bool p01 = v1 && (d0 == d1);
        const bool p23 = v3 && (d2 == d3);
#pragma unroll
        for (int j = 0; j < 4; ++j) {
            const int col = (4 * nw + j) * 16 + l15;
            float x0 = acc2[mt][j][0] * n0, x1 = acc2[mt][j][1] * n1;
            float x2 = acc2[mt][j][2] * n2, x3 = acc2[mt][j][3] * n3;
            if (uni) {
                atomAddF(agg + (long long)d0 * 256 + col, (x0 + x1) + (x2 + x3));
            } else {
                if (p01) atomAddF(agg + (long long)d0 * 256 + col, x0 + x1);
                else {
                    if (v0) atomAddF(agg + (long long)d0 * 256 + col, x0);
                    if (v1) atomAddF(agg + (long long)d1 * 256 + col, x1);
                }
                if (p23) atomAddF(agg + (long long)d2 * 256 + col, x2 + x3);
                else {
                    if (v2) atomAddF(agg + (long long)d2 * 256 + col, x2);
                    if (v3) atomAddF(agg + (long long)d3 * 256 + col, x3);
                }
            }
        }
    }
}

// ---------------------------------------------------------------------------
// stats: per-column sum / sumsq of h (= d_out) for BN
// ---------------------------------------------------------------------------
__global__ __launch_bounds__(256) void stats_kernel(
    const float* __restrict__ h, float* __restrict__ s1g,
    float* __restrict__ s2g, long long tot4) {
    __shared__ float s1l[256], s2l[256];
    const int t = threadIdx.x;
    s1l[t] = 0.f;
    s2l[t] = 0.f;
    __syncthreads();
    const int dg = t & 63;
    float a1[4] = {0.f, 0.f, 0.f, 0.f}, a2[4] = {0.f, 0.f, 0.f, 0.f};
    const long long stride = (long long)gridDim.x * 256;
    for (long long i4 = (long long)blockIdx.x * 256 + t; i4 < tot4; i4 += stride) {
        float4 v = ((const float4*)h)[i4];
        a1[0] += v.x; a2[0] += v.x * v.x;
        a1[1] += v.y; a2[1] += v.y * v.y;
        a1[2] += v.z; a2[2] += v.z * v.z;
        a1[3] += v.w; a2[3] += v.w * v.w;
    }
#pragma unroll
    for (int c = 0; c < 4; ++c) {
        atomicAdd(&s1l[dg * 4 + c], a1[c]);
        atomicAdd(&s2l[dg * 4 + c], a2[c]);
    }
    __syncthreads();
    atomAddF(&s1g[t], s1l[t]);
    atomAddF(&s2g[t], s2l[t]);
}

// ---------------------------------------------------------------------------
// finalize: out = tanh((h - mean) * rsqrt(var + eps) * gamma + beta)
// ---------------------------------------------------------------------------
__global__ __launch_bounds__(256) void finalize_kernel(
    float* __restrict__ out, const float* __restrict__ s1g,
    const float* __restrict__ s2g, const float* __restrict__ gamma,
    const float* __restrict__ beta, int N) {
    long long i4 = (long long)blockIdx.x * blockDim.x + threadIdx.x;
    long long tot = (long long)N * 64;
    if (i4 >= tot) return;
    const int dg = (int)(i4 & 63);
    float4 h = ((float4*)out)[i4];
    const float4 s1 = ((const float4*)s1g)[dg];
    const float4 s2 = ((const float4*)s2g)[dg];
    const float4 g = ((const float4*)gamma)[dg];
    const float4 b = ((const float4*)beta)[dg];
    const float invN = 1.f / (float)N;
    float4 o;
    { float m = s1.x * invN; float v = s2.x * invN - m * m;
      o.x = tanhf(fmaf(h.x - m, rsqrtf(v + BN_EPS) * g.x, b.x)); }
    { float m = s1.y * invN; float v = s2.y * invN - m * m;
      o.y = tanhf(fmaf(h.y - m, rsqrtf(v + BN_EPS) * g.y, b.y)); }
    { float m = s1.z * invN; float v = s2.z * invN - m * m;
      o.z = tanhf(fmaf(h.z - m, rsqrtf(v + BN_EPS) * g.z, b.z)); }
    { float m = s1.w * invN; float v = s2.w * invN - m * m;
      o.w = tanhf(fmaf(h.w - m, rsqrtf(v + BN_EPS) * g.w, b.w)); }
    ((float4*)out)[i4] = o;
}

// ---------------------------------------------------------------------------
extern "C" void kernel_launch(void* const* d_in, const int* in_sizes, int n_in,
                              void* d_out, int out_size, void* d_ws, size_t ws_size,
                              hipStream_t stream) {
    const float* node_ft  = (const float*)d_in[0];
    const float* edge_ft  = (const float*)d_in[1];
    const float* norm     = (const float*)d_in[2];
    const float* w_loop   = (const float*)d_in[3];
    const float* w_in     = (const float*)d_in[4];
    const float* loop_rel = (const float*)d_in[5];
    const float* w_bias   = (const float*)d_in[6];
    const float* bn_gamma = (const float*)d_in[7];
    const float* bn_beta  = (const float*)d_in[8];
    const int*   src      = (const int*)d_in[9];
    const int*   dst      = (const int*)d_in[10];

    const int N = in_sizes[2];
    const int E = in_sizes[9];
    float* out = (float*)d_out;

    float* s1g = (float*)d_ws;
    float* s2g = s1g + 256;

    hipMemsetAsync(d_ws, 0, 512 * sizeof(float), stream);

    float* Wle_ptr = nullptr;
    hipGetSymbolAddress((void**)&Wle_ptr, HIP_SYMBOL(g_Wle));
    void* hist_ptr = nullptr;
    hipGetSymbolAddress(&hist_ptr, HIP_SYMBOL(g_hist));
    hipMemsetAsync(hist_ptr, 0, (size_t)N * sizeof(int), stream);

    const int sblk = (N + 511) / 512;
    const int eblk = (E + 511) / 512;

    // dst counting sort -> g_perm
    hist_kernel<<<eblk, 512, 0, stream>>>(dst, E);
    scanA_kernel<<<sblk, 512, 0, stream>>>(N);
    scanB_kernel<<<1, 128, 0, stream>>>(sblk);
    scanC_kernel<<<sblk, 512, 0, stream>>>(N);
    perm_kernel<<<eblk, 512, 0, stream>>>(dst, E);

    // constant packs
    wle_kernel<<<256, 256, 0, stream>>>(loop_rel, w_loop, Wle_ptr);
    fb_pack<<<8 * 20, 512, 0, stream>>>();
    cb_pack<<<9 * 16, 512, 0, stream>>>(w_in);
    wleb_pack<<<8 * 16, 512, 0, stream>>>();

    // node pass -> NF + (loop_msg + bias) in d_out
    nfloop_kernel<<<(N + 63) / 64, 512, 0, stream>>>(node_ft, w_bias, out, N);
    // fused edge pass, XCD-chunked over dst-sorted tiles
    edge_kernel<<<(E + 63) / 64, 512, 0, stream>>>(edge_ft, norm, src, dst, out, E);
    stats_kernel<<<1024, 256, 0, stream>>>(out, s1g, s2g, (long long)N * 64);
    finalize_kernel<<<(int)(((long long)N * 64 + 255) / 256), 256, 0, stream>>>(
        out, s1g, s2g, bn_gamma, bn_beta, N);
}